// Round 7
// baseline (383.328 us; speedup 1.0000x reference)
//
#include <hip/hip_runtime.h>
#include <hip/hip_bf16.h>
#include <math.h>

#define SCALE_ 0.04419417382415922f   // 512^-0.5
#define EPS_  1e-5f

typedef unsigned short u16;
typedef __attribute__((ext_vector_type(8))) short     bf16x8;
typedef __attribute__((ext_vector_type(4))) float     f32x4;
typedef __attribute__((ext_vector_type(8))) unsigned short u16x8;
typedef __attribute__((ext_vector_type(4))) unsigned short u16x4;

__device__ __forceinline__ u16 f2b(float f) {
  union { float f; unsigned int u; } x; x.f = f;
  unsigned int u = x.u;
  return (u16)((u + 0x7FFFu + ((u >> 16) & 1u)) >> 16);
}
__device__ __forceinline__ float b2f(u16 h) {
  union { unsigned int u; float f; } x; x.u = ((unsigned int)h) << 16;
  return x.f;
}
__device__ __forceinline__ void gload_lds16(const void* g, void* l) {
  __builtin_amdgcn_global_load_lds(
      (const __attribute__((address_space(1))) void*)g,
      (__attribute__((address_space(3))) void*)l, 16, 0, 0);
}

// ---------------------------------------------------------------------------
// Weight convert+transpose: Wt[n][k] = bf16(W[k][n]), 512x512, z selects weight
// ---------------------------------------------------------------------------
__global__ __launch_bounds__(256) void wconv(
    const float* W0, const float* W1, const float* W2,
    const float* W3, const float* W4, const float* W5, u16* wt)
{
  const float* W;
  switch (blockIdx.z) {
    case 0: W = W0; break; case 1: W = W1; break; case 2: W = W2; break;
    case 3: W = W3; break; case 4: W = W4; break; default: W = W5; break;
  }
  u16* Wt = wt + (size_t)blockIdx.z * 262144;
  const int k0 = blockIdx.x * 64, n0 = blockIdx.y * 64;
  __shared__ float T[64][68];
  const int tid = threadIdx.x;
#pragma unroll
  for (int it = 0; it < 4; ++it) {
    int L = it * 256 + tid;
    int r = L >> 4, cg = L & 15;
    float4 v = *reinterpret_cast<const float4*>(W + (size_t)(k0 + r) * 512 + n0 + cg * 4);
    T[r][cg * 4 + 0] = v.x; T[r][cg * 4 + 1] = v.y;
    T[r][cg * 4 + 2] = v.z; T[r][cg * 4 + 3] = v.w;
  }
  __syncthreads();
#pragma unroll
  for (int it = 0; it < 2; ++it) {
    int L = it * 256 + tid;
    int rn = L >> 3, kg = L & 7;
    u16x8 o;
#pragma unroll
    for (int e = 0; e < 8; ++e) o[e] = f2b(T[kg * 8 + e][rn]);
    *(u16x8*)(Wt + (size_t)(n0 + rn) * 512 + k0 + kg * 8) = o;
  }
}

// ---------------------------------------------------------------------------
// Projection GEMM v3: B direct from L2 into VGPRs (no LDS for B).
// C_bf16[128x128 tile] = bf16(A_f32) @ Bt^T + bias.  BK=64.
// 256 thr = 4 waves (2m x 2n), wave = 64x64 (acc 4x4).
// LDS: only A, double-buffered 2x16KB. One barrier per K-step.
// ---------------------------------------------------------------------------
__global__ __launch_bounds__(256, 3) void gemm_proj(
    const float* A0, const u16* Bt0, const float* bi0, u16* C0,
    const float* A1, const u16* Bt1, const float* bi1, u16* C1,
    const float* A2, const u16* Bt2, const float* bi2, u16* C2)
{
  const float *A, *bias; const u16* Bt; u16* C;
  if (blockIdx.z == 0)      { A = A0; Bt = Bt0; bias = bi0; C = C0; }
  else if (blockIdx.z == 1) { A = A1; Bt = Bt1; bias = bi1; C = C1; }
  else                      { A = A2; Bt = Bt2; bias = bi2; C = C2; }

  __shared__ u16 As[2][8192];   // 128 rows x 64 k each
  const int tid = threadIdx.x;
  const int lane = tid & 63, wid = tid >> 6;
  const int wr = wid >> 1, wc = wid & 1;
  const int l15 = lane & 15, lh = lane >> 4, l7 = lane & 7;
  const int m0 = blockIdx.x * 128, n0 = blockIdx.y * 128;

  const f32x4 fz = {0.f, 0.f, 0.f, 0.f};
  f32x4 acc[4][4];
#pragma unroll
  for (int m = 0; m < 4; ++m)
#pragma unroll
    for (int n = 0; n < 4; ++n) acc[m][n] = fz;

  int aoff[2];
#pragma unroll
  for (int kh = 0; kh < 2; ++kh)
    aoff[kh] = (wr * 64 + l15) * 128 + (((kh * 4 + lh) ^ l7) << 4);

  // B row pointers (L2-resident): row = n0 + wc*64 + nf*16 + l15, k base lh*8
  const u16* Brow[4];
#pragma unroll
  for (int nf = 0; nf < 4; ++nf)
    Brow[nf] = Bt + (size_t)(n0 + wc * 64 + nf * 16 + l15) * 512 + lh * 8;

  // A staging map: it 0..3, L = it*256+tid; row r = L>>3, phys slot s = L&7,
  // logical col c = s ^ (r&7); src 8 floats at A[(m0+r)*512 + k0 + c*8].
  float4 xa[4], xb[4];
#pragma unroll
  for (int it = 0; it < 4; ++it) {
    int L = it * 256 + tid;
    int r = L >> 3, s = L & 7;
    int c = s ^ (r & 7);
    const float* ga = A + (size_t)(m0 + r) * 512 + c * 8;
    xa[it] = *reinterpret_cast<const float4*>(ga);
    xb[it] = *reinterpret_cast<const float4*>(ga + 4);
  }
#pragma unroll
  for (int it = 0; it < 4; ++it) {
    int L = it * 256 + tid;
    u16x8 o;
    o[0] = f2b(xa[it].x); o[1] = f2b(xa[it].y);
    o[2] = f2b(xa[it].z); o[3] = f2b(xa[it].w);
    o[4] = f2b(xb[it].x); o[5] = f2b(xb[it].y);
    o[6] = f2b(xb[it].z); o[7] = f2b(xb[it].w);
    *(u16x8*)((char*)As[0] + L * 16) = o;
  }
  __syncthreads();

  for (int t = 0; t < 8; ++t) {
    const int cur = t & 1;
    // prefetch A(t+1) from HBM — latency hidden under B-load + MFMA
    if (t < 7) {
      const int kn = (t + 1) * 64;
#pragma unroll
      for (int it = 0; it < 4; ++it) {
        int L = it * 256 + tid;
        int r = L >> 3, s = L & 7;
        int c = s ^ (r & 7);
        const float* ga = A + (size_t)(m0 + r) * 512 + kn + c * 8;
        xa[it] = *reinterpret_cast<const float4*>(ga);
        xb[it] = *reinterpret_cast<const float4*>(ga + 4);
      }
    }
    // B fragments for this K-step, straight from L2
    bf16x8 bfr[2][4];
#pragma unroll
    for (int kh = 0; kh < 2; ++kh)
#pragma unroll
      for (int nf = 0; nf < 4; ++nf)
        bfr[kh][nf] = *(const bf16x8*)(Brow[nf] + t * 64 + kh * 32);
    // compute
#pragma unroll
    for (int kh = 0; kh < 2; ++kh) {
      bf16x8 af[4];
#pragma unroll
      for (int m = 0; m < 4; ++m)
        af[m] = *(const bf16x8*)((const char*)As[cur] + aoff[kh] + m * 2048);
#pragma unroll
      for (int m = 0; m < 4; ++m)
#pragma unroll
        for (int n = 0; n < 4; ++n)
          acc[m][n] = __builtin_amdgcn_mfma_f32_16x16x32_bf16(af[m], bfr[kh][n], acc[m][n], 0, 0, 0);
    }
    // publish A(t+1) into the other buffer (safe: its readers finished at t-1)
    if (t < 7) {
#pragma unroll
      for (int it = 0; it < 4; ++it) {
        int L = it * 256 + tid;
        u16x8 o;
        o[0] = f2b(xa[it].x); o[1] = f2b(xa[it].y);
        o[2] = f2b(xa[it].z); o[3] = f2b(xa[it].w);
        o[4] = f2b(xb[it].x); o[5] = f2b(xb[it].y);
        o[6] = f2b(xb[it].z); o[7] = f2b(xb[it].w);
        *(u16x8*)((char*)As[cur ^ 1] + L * 16) = o;
      }
    }
    __syncthreads();
  }

  const int gn0 = n0 + wc * 64 + l15;
  float bv[4];
#pragma unroll
  for (int n = 0; n < 4; ++n) bv[n] = bias[gn0 + n * 16];
#pragma unroll
  for (int m = 0; m < 4; ++m)
#pragma unroll
    for (int reg = 0; reg < 4; ++reg) {
      int gm = m0 + wr * 64 + m * 16 + lh * 4 + reg;
#pragma unroll
      for (int n = 0; n < 4; ++n)
        C[(size_t)gm * 512 + gn0 + n * 16] = f2b(acc[m][n][reg] + bv[n]);
    }
}

// ---------------------------------------------------------------------------
// Strip output GEMM, double-buffered: out_f32 = A_bf16 @ Bt^T + bias.
// ---------------------------------------------------------------------------
__global__ __launch_bounds__(512) void gemm_out(
    const u16* __restrict__ A, const u16* __restrict__ Bt,
    const float* __restrict__ bias, float* __restrict__ C)
{
  __shared__ u16 As[2][4096];
  __shared__ u16 Bs[2][16384];
  const int tid = threadIdx.x;
  const int lane = tid & 63, wid = tid >> 6;
  const int wr = wid >> 2, wcn = wid & 3;
  const int l15 = lane & 15, lh = lane >> 4;
  const int sx = (l15 >> 1) & 3;
  const int m0 = blockIdx.x * 128;
  const int rr = tid >> 2, sp = tid & 3;
  const int ssw = sp ^ ((rr >> 1) & 3);

  const f32x4 fz = {0.f, 0.f, 0.f, 0.f};
  f32x4 acc[4][8];
#pragma unroll
  for (int m = 0; m < 4; ++m)
#pragma unroll
    for (int n = 0; n < 8; ++n) acc[m][n] = fz;

  const int aoff0 = (wr * 64 + l15) * 64 + ((lh ^ sx) << 4);
  const int boff0 = (wcn * 128 + l15) * 64 + ((lh ^ sx) << 4);

  {
#pragma unroll
    for (int it = 0; it < 4; ++it)
      gload_lds16(Bt + (size_t)(it * 128 + rr) * 512 + ssw * 8,
                  (char*)Bs[0] + (it * 512 + wid * 64) * 16);
    gload_lds16(A + (size_t)(m0 + rr) * 512 + ssw * 8,
                (char*)As[0] + (wid * 64) * 16);
  }
  __syncthreads();

#pragma unroll 2
  for (int t = 0; t < 16; ++t) {
    const int cur = t & 1, nxt = cur ^ 1;
    if (t < 15) {
      const int k0 = (t + 1) * 32;
#pragma unroll
      for (int it = 0; it < 4; ++it)
        gload_lds16(Bt + (size_t)(it * 128 + rr) * 512 + k0 + ssw * 8,
                    (char*)Bs[nxt] + (it * 512 + wid * 64) * 16);
      gload_lds16(A + (size_t)(m0 + rr) * 512 + k0 + ssw * 8,
                  (char*)As[nxt] + (wid * 64) * 16);
    }
    bf16x8 af[4], bfr[8];
#pragma unroll
    for (int m = 0; m < 4; ++m)
      af[m] = *(const bf16x8*)((const char*)As[cur] + aoff0 + m * 1024);
#pragma unroll
    for (int n = 0; n < 8; ++n)
      bfr[n] = *(const bf16x8*)((const char*)Bs[cur] + boff0 + n * 1024);
#pragma unroll
    for (int m = 0; m < 4; ++m)
#pragma unroll
      for (int n = 0; n < 8; ++n)
        acc[m][n] = __builtin_amdgcn_mfma_f32_16x16x32_bf16(af[m], bfr[n], acc[m][n], 0, 0, 0);
    __syncthreads();
  }

  const int gn0 = wcn * 128 + l15;
  float bv[8];
#pragma unroll
  for (int n = 0; n < 8; ++n) bv[n] = bias[gn0 + n * 16];
#pragma unroll
  for (int m = 0; m < 4; ++m)
#pragma unroll
    for (int reg = 0; reg < 4; ++reg) {
      int gm = m0 + wr * 64 + m * 16 + lh * 4 + reg;
#pragma unroll
      for (int n = 0; n < 8; ++n)
        C[(size_t)gm * 512 + gn0 + n * 16] = acc[m][n][reg] + bv[n];
    }
}

// ---------------------------------------------------------------------------
// pq/pk GEMM (small): bf16 out. 128x128 tiles, z selects set. Bt is [n][k].
// ---------------------------------------------------------------------------
__global__ __launch_bounds__(256) void gemm_pp(
    const u16* __restrict__ A,
    const u16* __restrict__ Bt0, const float* __restrict__ bi0, u16* __restrict__ C0,
    const u16* __restrict__ Bt1, const float* __restrict__ bi1, u16* __restrict__ C1)
{
  const u16* Bt; const float* bias; u16* C;
  if (blockIdx.z == 0) { Bt = Bt0; bias = bi0; C = C0; }
  else                 { Bt = Bt1; bias = bi1; C = C1; }

  __shared__ u16 As[8192];   // 128 x 64
  __shared__ u16 Bs[8192];   // 128 x 64
  const int tid = threadIdx.x;
  const int lane = tid & 63, wid = tid >> 6;
  const int wr = wid >> 1, wc = wid & 1;
  const int l15 = lane & 15, lh = lane >> 4, l7 = lane & 7;
  const int m0 = blockIdx.x * 128, n0 = blockIdx.y * 128;

  const f32x4 fz = {0.f, 0.f, 0.f, 0.f};
  f32x4 acc[4][4];
#pragma unroll
  for (int m = 0; m < 4; ++m)
#pragma unroll
    for (int n = 0; n < 4; ++n) acc[m][n] = fz;

  int aoff[2], boff[2];
#pragma unroll
  for (int kh = 0; kh < 2; ++kh) {
    int slot = ((kh * 4 + lh) ^ l7) << 4;
    aoff[kh] = (wr * 64 + l15) * 128 + slot;
    boff[kh] = (wc * 64 + l15) * 128 + slot;
  }

  for (int k0 = 0; k0 < 512; k0 += 64) {
    __syncthreads();
#pragma unroll
    for (int it = 0; it < 4; ++it) {
      int L = it * 256 + tid;
      int r = L >> 3, s = L & 7;
      int c = s ^ (r & 7);
      gload_lds16(A  + (size_t)(m0 + r) * 512 + k0 + c * 8,
                  (char*)As + (it * 256 + wid * 64) * 16);
      gload_lds16(Bt + (size_t)(n0 + r) * 512 + k0 + c * 8,
                  (char*)Bs + (it * 256 + wid * 64) * 16);
    }
    __syncthreads();
#pragma unroll
    for (int kh = 0; kh < 2; ++kh) {
      bf16x8 af[4], bfr[4];
#pragma unroll
      for (int m = 0; m < 4; ++m)
        af[m] = *(const bf16x8*)((const char*)As + aoff[kh] + m * 2048);
#pragma unroll
      for (int n = 0; n < 4; ++n)
        bfr[n] = *(const bf16x8*)((const char*)Bs + boff[kh] + n * 2048);
#pragma unroll
      for (int m = 0; m < 4; ++m)
#pragma unroll
        for (int n = 0; n < 4; ++n)
          acc[m][n] = __builtin_amdgcn_mfma_f32_16x16x32_bf16(af[m], bfr[n], acc[m][n], 0, 0, 0);
    }
  }

  const int gn0 = n0 + wc * 64 + l15;
  float bv[4];
#pragma unroll
  for (int n = 0; n < 4; ++n) bv[n] = bias[gn0 + n * 16];
#pragma unroll
  for (int m = 0; m < 4; ++m)
#pragma unroll
    for (int reg = 0; reg < 4; ++reg) {
      int gm = m0 + wr * 64 + m * 16 + lh * 4 + reg;
#pragma unroll
      for (int n = 0; n < 4; ++n)
        C[(size_t)gm * 512 + gn0 + n * 16] = f2b(acc[m][n][reg] + bv[n]);
    }
}

// ---------------------------------------------------------------------------
// qk_mfma: expS[bh][wq][wk] = exp(SCALE * pq_h[wq] . pk_h[wk]) via MFMA.
// ---------------------------------------------------------------------------
__global__ __launch_bounds__(256) void qk_mfma(
    const u16* __restrict__ pq, const u16* __restrict__ pk, u16* __restrict__ expS)
{
  __shared__ u16 As[8192];   // 128 x 64
  __shared__ u16 Bs[8192];
  const int tid = threadIdx.x;
  const int lane = tid & 63, wid = tid >> 6;
  const int wr = wid >> 1, wc = wid & 1;
  const int l15 = lane & 15, lh = lane >> 4, l7 = lane & 7;
  const int bh = blockIdx.z, b = bh >> 3, h = bh & 7;
  const int wq0 = blockIdx.x * 128, wk0 = blockIdx.y * 128;

  const f32x4 fz = {0.f, 0.f, 0.f, 0.f};
  f32x4 acc[4][4];
#pragma unroll
  for (int m = 0; m < 4; ++m)
#pragma unroll
    for (int n = 0; n < 4; ++n) acc[m][n] = fz;

#pragma unroll
  for (int it = 0; it < 4; ++it) {
    int L = it * 256 + tid;
    int r = L >> 3, s = L & 7;
    int c = s ^ (r & 7);
    gload_lds16(pq + ((size_t)b * 512 + wq0 + r) * 512 + h * 64 + c * 8,
                (char*)As + (it * 256 + wid * 64) * 16);
    gload_lds16(pk + ((size_t)b * 512 + wk0 + r) * 512 + h * 64 + c * 8,
                (char*)Bs + (it * 256 + wid * 64) * 16);
  }
  __syncthreads();

#pragma unroll
  for (int kh = 0; kh < 2; ++kh) {
    int slot = ((kh * 4 + lh) ^ l7) << 4;
    int aoff = (wr * 64 + l15) * 128 + slot;
    int boff = (wc * 64 + l15) * 128 + slot;
    bf16x8 af[4], bfr[4];
#pragma unroll
    for (int m = 0; m < 4; ++m)
      af[m] = *(const bf16x8*)((const char*)As + aoff + m * 2048);
#pragma unroll
    for (int n = 0; n < 4; ++n)
      bfr[n] = *(const bf16x8*)((const char*)Bs + boff + n * 2048);
#pragma unroll
    for (int m = 0; m < 4; ++m)
#pragma unroll
      for (int n = 0; n < 4; ++n)
        acc[m][n] = __builtin_amdgcn_mfma_f32_16x16x32_bf16(af[m], bfr[n], acc[m][n], 0, 0, 0);
  }

  const int gn0 = wk0 + wc * 64 + l15;
#pragma unroll
  for (int m = 0; m < 4; ++m)
#pragma unroll
    for (int reg = 0; reg < 4; ++reg) {
      int gm = wq0 + wr * 64 + m * 16 + lh * 4 + reg;
#pragma unroll
      for (int n = 0; n < 4; ++n)
        expS[((size_t)bh * 512 + gm) * 512 + gn0 + n * 16] =
            f2b(expf(acc[m][n][reg] * SCALE_));
    }
}

// ---------------------------------------------------------------------------
// Window attention (bf16 in/out), fused q 5-tap smoothing. fp32 math.
// One 64-thread block per (h, w, b).  [round-5 proven config]
// ---------------------------------------------------------------------------
__global__ __launch_bounds__(64) void attn_win(
    const u16* kp, const u16* vp, const u16* qp0, u16* attn)
{
  const int h = blockIdx.x, w = blockIdx.y, b = blockIdx.z;
  const int t = threadIdx.x;
  __shared__ float ks[8][68], vs[8][68], qr[12][68], qs[8][68], Ps[8][9];
  const size_t base = ((size_t)b * 4096 + (size_t)w * 8) * 512 + h * 64;

  {
    int i = t >> 3, dg = t & 7;
    u16x8 kv = *(const u16x8*)(kp + base + (size_t)i * 512 + dg * 8);
    u16x8 vv = *(const u16x8*)(vp + base + (size_t)i * 512 + dg * 8);
#pragma unroll
    for (int e = 0; e < 8; ++e) {
      ks[i][dg * 8 + e] = b2f(kv[e]);
      vs[i][dg * 8 + e] = b2f(vv[e]);
    }
  }
#pragma unroll
  for (int l = 0; l < 2; ++l) {
    int L = t + l * 64;
    if (L < 96) {
      int i = L >> 3, dg = L & 7;
      int m = w * 8 - 2 + i;
      if (m >= 0 && m < 4096) {
        u16x8 qv = *(const u16x8*)(qp0 + ((size_t)b * 4096 + m) * 512 + h * 64 + dg * 8);
#pragma unroll
        for (int e = 0; e < 8; ++e) qr[i][dg * 8 + e] = b2f(qv[e]);
      } else {
#pragma unroll
        for (int e = 0; e < 8; ++e) qr[i][dg * 8 + e] = 0.0f;
      }
    }
  }
  __syncthreads();
#pragma unroll
  for (int j = 0; j < 8; ++j)
    qs[j][t] = 0.2f * (qr[j][t] + qr[j + 1][t] + qr[j + 2][t] + qr[j + 3][t] + qr[j + 4][t]);
  __syncthreads();

  const int qi = t >> 3, kj = t & 7;
  float s = 0.0f;
#pragma unroll
  for (int d = 0; d < 64; ++d) s = fmaf(qs[qi][d], ks[kj][d], s);
  s *= SCALE_;
  float mx = s;
  mx = fmaxf(mx, __shfl_xor(mx, 1));
  mx = fmaxf(mx, __shfl_xor(mx, 2));
  mx = fmaxf(mx, __shfl_xor(mx, 4));
  float e = expf(s - mx);
  float sum = e;
  sum += __shfl_xor(sum, 1);
  sum += __shfl_xor(sum, 2);
  sum += __shfl_xor(sum, 4);
  Ps[qi][kj] = e / sum;
  __syncthreads();

  float o[8];
#pragma unroll
  for (int c = 0; c < 8; ++c) o[c] = 0.0f;
#pragma unroll
  for (int tt = 0; tt < 8; ++tt) {
    float pw = Ps[qi][tt];
#pragma unroll
    for (int c = 0; c < 8; ++c) o[c] = fmaf(pw, vs[tt][kj * 8 + c], o[c]);
  }
  u16x8 ov;
#pragma unroll
  for (int c = 0; c < 8; ++c) ov[c] = f2b(o[c]);
  *(u16x8*)(attn + base + (size_t)qi * 512 + kj * 8) = ov;
}

// ---------------------------------------------------------------------------
// Build pvT[bh][n=t*64+d][w2] = attn[b][8*w2+t+1][h*64+d]  (bf16)
// ---------------------------------------------------------------------------
__global__ __launch_bounds__(256) void pvt_build(const u16* attn, u16* pvT)
{
  const int bh = blockIdx.x;
  const int b = bh >> 3, h = bh & 7;
  const int w0 = blockIdx.y * 32;
  __shared__ u16 TL[448 * 40];
  const int tid = threadIdx.x;
#pragma unroll
  for (int it = 0; it < 8; ++it) {
    int L = it * 256 + tid;
    int dg = L & 7, r = L >> 3;
    int w2l = r >> 3, tt = r & 7;
    if (tt < 7) {
      int m = 8 * (w0 + w2l) + tt + 1;
      u16x8 v = *(const u16x8*)(attn + ((size_t)b * 4096 + m) * 512 + h * 64 + dg * 8);
#pragma unroll
      for (int e = 0; e < 8; ++e)
        TL[(tt * 64 + dg * 8 + e) * 40 + w2l] = v[e];
    }
  }
  __syncthreads();
#pragma unroll
  for (int it = 0; it < 7; ++it) {
    int L = it * 256 + tid;
    int n = L >> 2, seg = L & 3;
    u16x8 v = *(const u16x8*)(&TL[n * 40 + seg * 8]);
    *(u16x8*)(pvT + ((size_t)bh * 448 + n) * 512 + w0 + seg * 8) = v;
  }
}

// ---------------------------------------------------------------------------
// LayerNorm + exact GELU on window token 0 (bf16 in/out). One wave per row.
// ---------------------------------------------------------------------------
__global__ __launch_bounds__(64) void ln_gelu(
    const u16* attn, const float* g, const float* be, u16* wt)
{
  const int r = blockIdx.x;            // r = b*512 + w
  const int b = r >> 9, w = r & 511;
  const int t = threadIdx.x;
  const u16* x = attn + (((size_t)b * 4096) + (size_t)w * 8) * 512;

  u16x8 v = *(const u16x8*)(x + t * 8);
  float xv[8];
  float s1 = 0.f, s2 = 0.f;
#pragma unroll
  for (int e = 0; e < 8; ++e) {
    xv[e] = b2f(v[e]);
    s1 += xv[e]; s2 += xv[e] * xv[e];
  }
#pragma unroll
  for (int off = 1; off < 64; off <<= 1) {
    s1 += __shfl_xor(s1, off);
    s2 += __shfl_xor(s2, off);
  }
  const float mu  = s1 * (1.0f / 512.0f);
  const float var = s2 * (1.0f / 512.0f) - mu * mu;
  const float inv = 1.0f / sqrtf(var + EPS_);

  const int d0 = t * 8;
  float4 g0 = *reinterpret_cast<const float4*>(g + d0);
  float4 g1 = *reinterpret_cast<const float4*>(g + d0 + 4);
  float4 b0 = *reinterpret_cast<const float4*>(be + d0);
  float4 b1 = *reinterpret_cast<const float4*>(be + d0 + 4);
  float gv[8] = {g0.x, g0.y, g0.z, g0.w, g1.x, g1.y, g1.z, g1.w};
  float bvv[8] = {b0.x, b0.y, b0.z, b0.w, b1.x, b1.y, b1.z, b1.w};
  const float k2 = 0.70710678118654752f;
  u16x8 ov;
#pragma unroll
  for (int e = 0; e < 8; ++e) {
    float y = (xv[e] - mu) * inv * gv[e] + bvv[e];
    ov[e] = f2b(0.5f * y * (1.0f + erff(y * k2)));
  }
  *(u16x8*)(wt + (size_t)r * 512 + d0) = ov;
}

// ---------------------------------------------------------------------------
// rsinv[row] = 1 / sum_k expS[row][k]  (bf16 in). 4 rows per 256-thread block.
// ---------------------------------------------------------------------------
__global__ __launch_bounds__(256) void rs_inv(const u16* expS, float* rsinv)
{
  const int row = blockIdx.x * 4 + (threadIdx.x >> 6);
  const int t = threadIdx.x & 63;
  u16x8 v = *(const u16x8*)(expS + (size_t)row * 512 + t * 8);
  float s = 0.f;
#pragma unroll
  for (int e = 0; e < 8; ++e) s += b2f(v[e]);
#pragma unroll
  for (int off = 1; off < 64; off <<= 1) s += __shfl_xor(s, off);
  if (t == 0) rsinv[row] = 1.0f / s;
}

// ---------------------------------------------------------------------------
// PV MFMA GEMM + rescale + residual. Grid: x = t (7), y = m-strip (4), z = bh.
// ---------------------------------------------------------------------------
__global__ __launch_bounds__(256) void pv_mfma(
    const u16* __restrict__ expS, const u16* __restrict__ pvT,
    const float* __restrict__ rsinv, const u16* __restrict__ attn,
    u16* __restrict__ X2)
{
  __shared__ u16 As[8192];   // 128 x 64
  __shared__ u16 Bs[4096];   // 64 x 64
  const int tid = threadIdx.x;
  const int lane = tid & 63, wid = tid >> 6;
  const int wr = wid >> 1, wc = wid & 1;
  const int l15 = lane & 15, lh = lane >> 4, l7 = lane & 7;
  const int bh = blockIdx.z, b = bh >> 3, h = bh & 7;
  const int m0 = blockIdx.y * 128;
  const int nt = blockIdx.x;           // t in [0,7)

  const f32x4 fz = {0.f, 0.f, 0.f, 0.f};
  f32x4 acc[4][2];
#pragma unroll
  for (int m = 0; m < 4; ++m)
#pragma unroll
    for (int n = 0; n < 2; ++n) acc[m][n] = fz;

  int aoff[2], boff[2];
#pragma unroll
  for (int kh = 0; kh < 2; ++kh) {
    int slot = ((kh * 4 + lh) ^ l7) << 4;
    aoff[kh] = (wr * 64 + l15) * 128 + slot;
    boff[kh] = (wc * 32 + l15) * 128 + slot;
  }

  for (int k0 = 0; k0 < 512; k0 += 64) {
    __syncthreads();
#pragma unroll
    for (int it = 0; it < 4; ++it) {
      int L = it * 256 + tid;
      int r = L >> 3, s = L & 7;
      int c = s ^ (r & 7);
      gload_lds16(expS + ((size_t)bh * 512 + m0 + r) * 512 + k0 + c * 8,
                  (char*)As + (it * 256 + wid * 64) * 16);
    }
#pragma unroll
    for (int it = 0; it < 2; ++it) {
      int L = it * 256 + tid;
      int r = L >> 3, s = L & 7;
      int c = s ^ (r & 7);
      gload_lds16(pvT + ((size_t)bh * 448 + nt * 64 + r) * 512 + k0 + c * 8,
                  (char*)Bs + (it * 256 + wid * 64) * 16);
    }
    __syncthreads();
#pragma unroll
    for (int kh = 0; kh < 2; ++kh) {
      bf16x8 af[4], bfr[2];
#pragma unroll
      for (int m = 0; m < 4; ++m)
        af[m] = *(const bf16x8*)((const char*)As + aoff[kh] + m * 2048);
#pragma unroll
      for (int n = 0; n < 2; ++n)
        bfr[n] = *(const bf16x8*)((const char*)Bs + boff[kh] + n * 2048);
#pragma unroll
      for (int m = 0; m < 4; ++m)
#pragma unroll
        for (int n = 0; n < 2; ++n)
          acc[m][n] = __builtin_amdgcn_mfma_f32_16x16x32_bf16(af[m], bfr[n], acc[m][n], 0, 0, 0);
    }
  }

#pragma unroll
  for (int m = 0; m < 4; ++m)
#pragma unroll
    for (int reg = 0; reg < 4; ++reg) {
      int gm = m0 + wr * 64 + m * 16 + lh * 4 + reg;      // wq
      float ri = rsinv[bh * 512 + gm];
#pragma unroll
      for (int n = 0; n < 2; ++n) {
        int d = wc * 32 + n * 16 + l15;
        float res = b2f(attn[((size_t)b * 4096 + gm * 8 + nt + 1) * 512 + h * 64 + d]);
        X2[((size_t)b * 3584 + gm * 7 + nt) * 512 + h * 64 + d] =
            f2b(acc[m][n][reg] * ri + res);
      }
    }
}

// ---------------------------------------------------------------------------
extern "C" void kernel_launch(void* const* d_in, const int* in_sizes, int n_in,
                              void* d_out, int out_size, void* d_ws, size_t ws_size,
                              hipStream_t stream)
{
  const float* k_in = (const float*)d_in[0];
  const float* v_in = (const float*)d_in[1];
  const float* q_in = (const float*)d_in[2];
  const float* Wk  = (const float*)d_in[4];
  const float* bk  = (const float*)d_in[5];
  const float* Wv  = (const float*)d_in[6];
  const float* bv  = (const float*)d_in[7];
  const float* Wq  = (const float*)d_in[8];
  const float* bq  = (const float*)d_in[9];
  const float* lng = (const float*)d_in[10];
  const float* lnb = (const float*)d_in[11];
  const float* Wpq = (const float*)d_in[12];
  const float* bpq = (const float*)d_in[13];
  const float* Wpk = (const float*)d_in[14];
  const float* bpk = (const float*)d_in[15];
  const float* Wo  = (const float*)d_in[16];
  const float* bo  = (const float*)d_in[17];
  float* out = (float*)d_out;

  char* ws = (char*)d_ws;
  const size_t MB = 1024 * 1024;
  u16* wtb  = (u16*)(ws);                 // 6 x 512KB transposed bf16 weights
  u16* kp   = (u16*)(ws + 16 * MB);
  u16* vp   = (u16*)(ws + 52 * MB);
  u16* qp0  = (u16*)(ws + 88 * MB);
  u16* attn = (u16*)(ws + 124 * MB);
  // phase 2 (kp/vp/qp0 regions reused after attn_win)
  u16*   wt    = (u16*)(ws + 16 * MB);
  u16*   pq    = (u16*)(ws + 20 * MB);
  u16*   pk    = (u16*)(ws + 28 * MB);
  float* rsinv = (float*)(ws + 36 * MB);
  u16*   expS  = (u16*)(ws + 40 * MB);
  u16*   pvT   = (u16*)(ws + 76 * MB);
  u16*   X2    = (u16*)(ws + 160 * MB);

  u16* Wkt  = wtb;
  u16* Wvt  = wtb + 1 * 262144;
  u16* Wqt  = wtb + 2 * 262144;
  u16* Wpqt = wtb + 3 * 262144;
  u16* Wpkt = wtb + 4 * 262144;
  u16* Wot  = wtb + 5 * 262144;

  wconv<<<dim3(8, 8, 6), 256, 0, stream>>>(Wk, Wv, Wq, Wpq, Wpk, Wo, wtb);

  // B-direct-from-L2 projection GEMMs (k, v, q)
  gemm_proj<<<dim3(256, 4, 3), 256, 0, stream>>>(
      k_in, Wkt, bk, kp,
      v_in, Wvt, bv, vp,
      q_in, Wqt, bq, qp0);

  attn_win<<<dim3(8, 512, 8), 64, 0, stream>>>(kp, vp, qp0, attn);
  pvt_build<<<dim3(64, 16), 256, 0, stream>>>(attn, pvT);
  ln_gelu<<<4096, 64, 0, stream>>>(attn, lng, lnb, wt);

  gemm_pp<<<dim3(32, 4, 2), 256, 0, stream>>>(
      wt, Wpqt, bpq, pq, Wpkt, bpk, pk);

  qk_mfma<<<dim3(4, 4, 64), 256, 0, stream>>>(pq, pk, expS);
  rs_inv<<<8192, 256, 0, stream>>>(expS, rsinv);
  pv_mfma<<<dim3(7, 4, 64), 256, 0, stream>>>(expS, pvT, rsinv, attn, X2);

  gemm_out<<<dim3(224, 1, 1), 512, 0, stream>>>(X2, Wot, bo, out);
}

// Round 8
// 288.056 us; speedup vs baseline: 1.3307x; 1.3307x over previous
//
#include <hip/hip_runtime.h>
#include <hip/hip_bf16.h>
#include <math.h>

#define SCALE_ 0.04419417382415922f   // 512^-0.5
#define EPS_  1e-5f

typedef unsigned short u16;
typedef __attribute__((ext_vector_type(8))) short     bf16x8;
typedef __attribute__((ext_vector_type(4))) float     f32x4;
typedef __attribute__((ext_vector_type(8))) unsigned short u16x8;
typedef __attribute__((ext_vector_type(4))) unsigned short u16x4;

__device__ __forceinline__ u16 f2b(float f) {
  union { float f; unsigned int u; } x; x.f = f;
  unsigned int u = x.u;
  return (u16)((u + 0x7FFFu + ((u >> 16) & 1u)) >> 16);
}
__device__ __forceinline__ float b2f(u16 h) {
  union { unsigned int u; float f; } x; x.u = ((unsigned int)h) << 16;
  return x.f;
}
__device__ __forceinline__ void gload_lds16(const void* g, void* l) {
  __builtin_amdgcn_global_load_lds(
      (const __attribute__((address_space(1))) void*)g,
      (__attribute__((address_space(3))) void*)l, 16, 0, 0);
}

// ---------------------------------------------------------------------------
// Weight convert+transpose: Wt[n][k] = bf16(W[k][n]), 512x512, z selects weight
// ---------------------------------------------------------------------------
__global__ __launch_bounds__(256) void wconv(
    const float* W0, const float* W1, const float* W2,
    const float* W3, const float* W4, const float* W5, u16* wt)
{
  const float* W;
  switch (blockIdx.z) {
    case 0: W = W0; break; case 1: W = W1; break; case 2: W = W2; break;
    case 3: W = W3; break; case 4: W = W4; break; default: W = W5; break;
  }
  u16* Wt = wt + (size_t)blockIdx.z * 262144;
  const int k0 = blockIdx.x * 64, n0 = blockIdx.y * 64;
  __shared__ float T[64][68];
  const int tid = threadIdx.x;
#pragma unroll
  for (int it = 0; it < 4; ++it) {
    int L = it * 256 + tid;
    int r = L >> 4, cg = L & 15;
    float4 v = *reinterpret_cast<const float4*>(W + (size_t)(k0 + r) * 512 + n0 + cg * 4);
    T[r][cg * 4 + 0] = v.x; T[r][cg * 4 + 1] = v.y;
    T[r][cg * 4 + 2] = v.z; T[r][cg * 4 + 3] = v.w;
  }
  __syncthreads();
#pragma unroll
  for (int it = 0; it < 2; ++it) {
    int L = it * 256 + tid;
    int rn = L >> 3, kg = L & 7;
    u16x8 o;
#pragma unroll
    for (int e = 0; e < 8; ++e) o[e] = f2b(T[kg * 8 + e][rn]);
    *(u16x8*)(Wt + (size_t)(n0 + rn) * 512 + k0 + kg * 8) = o;
  }
}

// ---------------------------------------------------------------------------
// Strip projection GEMM (round-4 proven, ~120us): full-N strip, BK=64,
// C_bf16[128 x 512] = bf16(A_f32) @ Bt^T + bias. 512 thr = 8 waves (2Mx4N).
// ---------------------------------------------------------------------------
__global__ __launch_bounds__(512) void gemm_proj(
    const float* A0, const u16* Bt0, const float* bi0, u16* C0,
    const float* A1, const u16* Bt1, const float* bi1, u16* C1,
    const float* A2, const u16* Bt2, const float* bi2, u16* C2)
{
  const float *A, *bias; const u16* Bt; u16* C;
  if (blockIdx.z == 0)      { A = A0; Bt = Bt0; bias = bi0; C = C0; }
  else if (blockIdx.z == 1) { A = A1; Bt = Bt1; bias = bi1; C = C1; }
  else                      { A = A2; Bt = Bt2; bias = bi2; C = C2; }

  __shared__ u16 As[8192];    // 128 rows x 64 k
  __shared__ u16 Bs[32768];   // 512 n-rows x 64 k
  const int tid = threadIdx.x;
  const int lane = tid & 63, wid = tid >> 6;
  const int wr = wid >> 2, wcn = wid & 3;          // 2 x 4 wave grid
  const int l15 = lane & 15, lh = lane >> 4, l7 = lane & 7;
  const int m0 = blockIdx.x * 128;

  const f32x4 fz = {0.f, 0.f, 0.f, 0.f};
  f32x4 acc[4][8];
#pragma unroll
  for (int m = 0; m < 4; ++m)
#pragma unroll
    for (int n = 0; n < 8; ++n) acc[m][n] = fz;

  int aoff[2], boff[2];
#pragma unroll
  for (int kh = 0; kh < 2; ++kh) {
    int slot = ((kh * 4 + lh) ^ l7) << 4;
    aoff[kh] = (wr * 64 + l15) * 128 + slot;
    boff[kh] = (wcn * 128 + l15) * 128 + slot;
  }

  for (int k0 = 0; k0 < 512; k0 += 64) {
    __syncthreads();
#pragma unroll
    for (int it = 0; it < 8; ++it) {
      int L = it * 512 + tid;
      int r = L >> 3, s = L & 7;
      int c = s ^ (r & 7);
      gload_lds16(Bt + (size_t)r * 512 + k0 + c * 8,
                  (char*)Bs + (it * 512 + wid * 64) * 16);
    }
    float4 xa[2], xb[2];
#pragma unroll
    for (int it = 0; it < 2; ++it) {
      int L = it * 512 + tid;
      int r = L >> 3, s = L & 7;
      int c = s ^ (r & 7);
      const float* ga = A + (size_t)(m0 + r) * 512 + k0 + c * 8;
      xa[it] = *reinterpret_cast<const float4*>(ga);
      xb[it] = *reinterpret_cast<const float4*>(ga + 4);
    }
#pragma unroll
    for (int it = 0; it < 2; ++it) {
      int L = it * 512 + tid;
      u16x8 o;
      o[0] = f2b(xa[it].x); o[1] = f2b(xa[it].y);
      o[2] = f2b(xa[it].z); o[3] = f2b(xa[it].w);
      o[4] = f2b(xb[it].x); o[5] = f2b(xb[it].y);
      o[6] = f2b(xb[it].z); o[7] = f2b(xb[it].w);
      *(u16x8*)((char*)As + L * 16) = o;
    }
    __syncthreads();
#pragma unroll
    for (int kh = 0; kh < 2; ++kh) {
      bf16x8 af[4], bfr[8];
#pragma unroll
      for (int m = 0; m < 4; ++m)
        af[m] = *(const bf16x8*)((const char*)As + aoff[kh] + m * 2048);
#pragma unroll
      for (int n = 0; n < 8; ++n)
        bfr[n] = *(const bf16x8*)((const char*)Bs + boff[kh] + n * 2048);
#pragma unroll
      for (int m = 0; m < 4; ++m)
#pragma unroll
        for (int n = 0; n < 8; ++n)
          acc[m][n] = __builtin_amdgcn_mfma_f32_16x16x32_bf16(af[m], bfr[n], acc[m][n], 0, 0, 0);
    }
  }

  const int gn0 = wcn * 128 + l15;
  float bv[8];
#pragma unroll
  for (int n = 0; n < 8; ++n) bv[n] = bias[gn0 + n * 16];
#pragma unroll
  for (int m = 0; m < 4; ++m)
#pragma unroll
    for (int reg = 0; reg < 4; ++reg) {
      int gm = m0 + wr * 64 + m * 16 + lh * 4 + reg;
#pragma unroll
      for (int n = 0; n < 8; ++n)
        C[(size_t)gm * 512 + gn0 + n * 16] = f2b(acc[m][n][reg] + bv[n]);
    }
}

// ---------------------------------------------------------------------------
// Strip output GEMM, double-buffered: out_f32 = A_bf16 @ Bt^T + bias.
// ---------------------------------------------------------------------------
__global__ __launch_bounds__(512) void gemm_out(
    const u16* __restrict__ A, const u16* __restrict__ Bt,
    const float* __restrict__ bias, float* __restrict__ C)
{
  __shared__ u16 As[2][4096];
  __shared__ u16 Bs[2][16384];
  const int tid = threadIdx.x;
  const int lane = tid & 63, wid = tid >> 6;
  const int wr = wid >> 2, wcn = wid & 3;
  const int l15 = lane & 15, lh = lane >> 4;
  const int sx = (l15 >> 1) & 3;
  const int m0 = blockIdx.x * 128;
  const int rr = tid >> 2, sp = tid & 3;
  const int ssw = sp ^ ((rr >> 1) & 3);

  const f32x4 fz = {0.f, 0.f, 0.f, 0.f};
  f32x4 acc[4][8];
#pragma unroll
  for (int m = 0; m < 4; ++m)
#pragma unroll
    for (int n = 0; n < 8; ++n) acc[m][n] = fz;

  const int aoff0 = (wr * 64 + l15) * 64 + ((lh ^ sx) << 4);
  const int boff0 = (wcn * 128 + l15) * 64 + ((lh ^ sx) << 4);

  {
#pragma unroll
    for (int it = 0; it < 4; ++it)
      gload_lds16(Bt + (size_t)(it * 128 + rr) * 512 + ssw * 8,
                  (char*)Bs[0] + (it * 512 + wid * 64) * 16);
    gload_lds16(A + (size_t)(m0 + rr) * 512 + ssw * 8,
                (char*)As[0] + (wid * 64) * 16);
  }
  __syncthreads();

#pragma unroll 2
  for (int t = 0; t < 16; ++t) {
    const int cur = t & 1, nxt = cur ^ 1;
    if (t < 15) {
      const int k0 = (t + 1) * 32;
#pragma unroll
      for (int it = 0; it < 4; ++it)
        gload_lds16(Bt + (size_t)(it * 128 + rr) * 512 + k0 + ssw * 8,
                    (char*)Bs[nxt] + (it * 512 + wid * 64) * 16);
      gload_lds16(A + (size_t)(m0 + rr) * 512 + k0 + ssw * 8,
                  (char*)As[nxt] + (wid * 64) * 16);
    }
    bf16x8 af[4], bfr[8];
#pragma unroll
    for (int m = 0; m < 4; ++m)
      af[m] = *(const bf16x8*)((const char*)As[cur] + aoff0 + m * 1024);
#pragma unroll
    for (int n = 0; n < 8; ++n)
      bfr[n] = *(const bf16x8*)((const char*)Bs[cur] + boff0 + n * 1024);
#pragma unroll
    for (int m = 0; m < 4; ++m)
#pragma unroll
      for (int n = 0; n < 8; ++n)
        acc[m][n] = __builtin_amdgcn_mfma_f32_16x16x32_bf16(af[m], bfr[n], acc[m][n], 0, 0, 0);
    __syncthreads();
  }

  const int gn0 = wcn * 128 + l15;
  float bv[8];
#pragma unroll
  for (int n = 0; n < 8; ++n) bv[n] = bias[gn0 + n * 16];
#pragma unroll
  for (int m = 0; m < 4; ++m)
#pragma unroll
    for (int reg = 0; reg < 4; ++reg) {
      int gm = m0 + wr * 64 + m * 16 + lh * 4 + reg;
#pragma unroll
      for (int n = 0; n < 8; ++n)
        C[(size_t)gm * 512 + gn0 + n * 16] = acc[m][n][reg] + bv[n];
    }
}

// ---------------------------------------------------------------------------
// pq/pk GEMM (small): bf16 out. 128x128 tiles, z selects set. Bt is [n][k].
// ---------------------------------------------------------------------------
__global__ __launch_bounds__(256) void gemm_pp(
    const u16* __restrict__ A,
    const u16* __restrict__ Bt0, const float* __restrict__ bi0, u16* __restrict__ C0,
    const u16* __restrict__ Bt1, const float* __restrict__ bi1, u16* __restrict__ C1)
{
  const u16* Bt; const float* bias; u16* C;
  if (blockIdx.z == 0) { Bt = Bt0; bias = bi0; C = C0; }
  else                 { Bt = Bt1; bias = bi1; C = C1; }

  __shared__ u16 As[8192];   // 128 x 64
  __shared__ u16 Bs[8192];   // 128 x 64
  const int tid = threadIdx.x;
  const int lane = tid & 63, wid = tid >> 6;
  const int wr = wid >> 1, wc = wid & 1;
  const int l15 = lane & 15, lh = lane >> 4, l7 = lane & 7;
  const int m0 = blockIdx.x * 128, n0 = blockIdx.y * 128;

  const f32x4 fz = {0.f, 0.f, 0.f, 0.f};
  f32x4 acc[4][4];
#pragma unroll
  for (int m = 0; m < 4; ++m)
#pragma unroll
    for (int n = 0; n < 4; ++n) acc[m][n] = fz;

  int aoff[2], boff[2];
#pragma unroll
  for (int kh = 0; kh < 2; ++kh) {
    int slot = ((kh * 4 + lh) ^ l7) << 4;
    aoff[kh] = (wr * 64 + l15) * 128 + slot;
    boff[kh] = (wc * 64 + l15) * 128 + slot;
  }

  for (int k0 = 0; k0 < 512; k0 += 64) {
    __syncthreads();
#pragma unroll
    for (int it = 0; it < 4; ++it) {
      int L = it * 256 + tid;
      int r = L >> 3, s = L & 7;
      int c = s ^ (r & 7);
      gload_lds16(A  + (size_t)(m0 + r) * 512 + k0 + c * 8,
                  (char*)As + (it * 256 + wid * 64) * 16);
      gload_lds16(Bt + (size_t)(n0 + r) * 512 + k0 + c * 8,
                  (char*)Bs + (it * 256 + wid * 64) * 16);
    }
    __syncthreads();
#pragma unroll
    for (int kh = 0; kh < 2; ++kh) {
      bf16x8 af[4], bfr[4];
#pragma unroll
      for (int m = 0; m < 4; ++m)
        af[m] = *(const bf16x8*)((const char*)As + aoff[kh] + m * 2048);
#pragma unroll
      for (int n = 0; n < 4; ++n)
        bfr[n] = *(const bf16x8*)((const char*)Bs + boff[kh] + n * 2048);
#pragma unroll
      for (int m = 0; m < 4; ++m)
#pragma unroll
        for (int n = 0; n < 4; ++n)
          acc[m][n] = __builtin_amdgcn_mfma_f32_16x16x32_bf16(af[m], bfr[n], acc[m][n], 0, 0, 0);
    }
  }

  const int gn0 = n0 + wc * 64 + l15;
  float bv[4];
#pragma unroll
  for (int n = 0; n < 4; ++n) bv[n] = bias[gn0 + n * 16];
#pragma unroll
  for (int m = 0; m < 4; ++m)
#pragma unroll
    for (int reg = 0; reg < 4; ++reg) {
      int gm = m0 + wr * 64 + m * 16 + lh * 4 + reg;
#pragma unroll
      for (int n = 0; n < 4; ++n)
        C[(size_t)gm * 512 + gn0 + n * 16] = f2b(acc[m][n][reg] + bv[n]);
    }
}

// ---------------------------------------------------------------------------
// qk_mfma: expS = exp(SCALE * pq . pk) via MFMA. XCD-coscheduled 1-D grid:
// blocks of one bh satisfy wgid % 64 == bh -> same XCD -> pq/pk L2-hot.
// ---------------------------------------------------------------------------
__global__ __launch_bounds__(256) void qk_mfma(
    const u16* __restrict__ pq, const u16* __restrict__ pk, u16* __restrict__ expS)
{
  __shared__ u16 As[8192];   // 128 x 64
  __shared__ u16 Bs[8192];
  const int tid = threadIdx.x;
  const int lane = tid & 63, wid = tid >> 6;
  const int wr = wid >> 1, wc = wid & 1;
  const int l15 = lane & 15, lh = lane >> 4, l7 = lane & 7;
  const int bh = blockIdx.x & 63;
  const int sidx = blockIdx.x >> 6;                 // 0..15
  const int b = bh >> 3, h = bh & 7;
  const int wq0 = (sidx & 3) * 128, wk0 = (sidx >> 2) * 128;

  const f32x4 fz = {0.f, 0.f, 0.f, 0.f};
  f32x4 acc[4][4];
#pragma unroll
  for (int m = 0; m < 4; ++m)
#pragma unroll
    for (int n = 0; n < 4; ++n) acc[m][n] = fz;

#pragma unroll
  for (int it = 0; it < 4; ++it) {
    int L = it * 256 + tid;
    int r = L >> 3, s = L & 7;
    int c = s ^ (r & 7);
    gload_lds16(pq + ((size_t)b * 512 + wq0 + r) * 512 + h * 64 + c * 8,
                (char*)As + (it * 256 + wid * 64) * 16);
    gload_lds16(pk + ((size_t)b * 512 + wk0 + r) * 512 + h * 64 + c * 8,
                (char*)Bs + (it * 256 + wid * 64) * 16);
  }
  __syncthreads();

#pragma unroll
  for (int kh = 0; kh < 2; ++kh) {
    int slot = ((kh * 4 + lh) ^ l7) << 4;
    int aoff = (wr * 64 + l15) * 128 + slot;
    int boff = (wc * 64 + l15) * 128 + slot;
    bf16x8 af[4], bfr[4];
#pragma unroll
    for (int m = 0; m < 4; ++m)
      af[m] = *(const bf16x8*)((const char*)As + aoff + m * 2048);
#pragma unroll
    for (int n = 0; n < 4; ++n)
      bfr[n] = *(const bf16x8*)((const char*)Bs + boff + n * 2048);
#pragma unroll
    for (int m = 0; m < 4; ++m)
#pragma unroll
      for (int n = 0; n < 4; ++n)
        acc[m][n] = __builtin_amdgcn_mfma_f32_16x16x32_bf16(af[m], bfr[n], acc[m][n], 0, 0, 0);
  }

  const int gn0 = wk0 + wc * 64 + l15;
#pragma unroll
  for (int m = 0; m < 4; ++m)
#pragma unroll
    for (int reg = 0; reg < 4; ++reg) {
      int gm = wq0 + wr * 64 + m * 16 + lh * 4 + reg;
#pragma unroll
      for (int n = 0; n < 4; ++n)
        expS[((size_t)bh * 512 + gm) * 512 + gn0 + n * 16] =
            f2b(expf(acc[m][n][reg] * SCALE_));
    }
}

// ---------------------------------------------------------------------------
// Window attention (bf16 in/out), fused q 5-tap smoothing. fp32 math.
// 4 waves per 256-thread block; wave wid handles head h = bx*4 + wid.
// Identical per-wave logic to the round-5 proven kernel.
// ---------------------------------------------------------------------------
__global__ __launch_bounds__(256) void attn_win(
    const u16* kp, const u16* vp, const u16* qp0, u16* attn)
{
  const int wid = threadIdx.x >> 6;
  const int t = threadIdx.x & 63;
  const int h = blockIdx.x * 4 + wid, w = blockIdx.y, b = blockIdx.z;
  __shared__ float ks[4][8][68], vs[4][8][68], qr[4][12][68], qs[4][8][68], Ps[4][8][9];
  const size_t base = ((size_t)b * 4096 + (size_t)w * 8) * 512 + h * 64;

  {
    int i = t >> 3, dg = t & 7;
    u16x8 kv = *(const u16x8*)(kp + base + (size_t)i * 512 + dg * 8);
    u16x8 vv = *(const u16x8*)(vp + base + (size_t)i * 512 + dg * 8);
#pragma unroll
    for (int e = 0; e < 8; ++e) {
      ks[wid][i][dg * 8 + e] = b2f(kv[e]);
      vs[wid][i][dg * 8 + e] = b2f(vv[e]);
    }
  }
#pragma unroll
  for (int l = 0; l < 2; ++l) {
    int L = t + l * 64;
    if (L < 96) {
      int i = L >> 3, dg = L & 7;
      int m = w * 8 - 2 + i;
      if (m >= 0 && m < 4096) {
        u16x8 qv = *(const u16x8*)(qp0 + ((size_t)b * 4096 + m) * 512 + h * 64 + dg * 8);
#pragma unroll
        for (int e = 0; e < 8; ++e) qr[wid][i][dg * 8 + e] = b2f(qv[e]);
      } else {
#pragma unroll
        for (int e = 0; e < 8; ++e) qr[wid][i][dg * 8 + e] = 0.0f;
      }
    }
  }
  // wave-local data, wave-local consumers: no cross-wave sync needed, but
  // LDS writes must land before reads in the SAME wave -> s_waitcnt only.
  __builtin_amdgcn_s_waitcnt(0);   // lgkmcnt(0)+vmcnt(0) conservative
#pragma unroll
  for (int j = 0; j < 8; ++j)
    qs[wid][j][t] = 0.2f * (qr[wid][j][t] + qr[wid][j + 1][t] + qr[wid][j + 2][t] +
                            qr[wid][j + 3][t] + qr[wid][j + 4][t]);
  __builtin_amdgcn_s_waitcnt(0);

  const int qi = t >> 3, kj = t & 7;
  float s = 0.0f;
#pragma unroll
  for (int d = 0; d < 64; ++d) s = fmaf(qs[wid][qi][d], ks[wid][kj][d], s);
  s *= SCALE_;
  float mx = s;
  mx = fmaxf(mx, __shfl_xor(mx, 1));
  mx = fmaxf(mx, __shfl_xor(mx, 2));
  mx = fmaxf(mx, __shfl_xor(mx, 4));
  float e = expf(s - mx);
  float sum = e;
  sum += __shfl_xor(sum, 1);
  sum += __shfl_xor(sum, 2);
  sum += __shfl_xor(sum, 4);
  Ps[wid][qi][kj] = e / sum;
  __builtin_amdgcn_s_waitcnt(0);

  float o[8];
#pragma unroll
  for (int c = 0; c < 8; ++c) o[c] = 0.0f;
#pragma unroll
  for (int tt = 0; tt < 8; ++tt) {
    float pw = Ps[wid][qi][tt];
#pragma unroll
    for (int c = 0; c < 8; ++c) o[c] = fmaf(pw, vs[wid][tt][kj * 8 + c], o[c]);
  }
  u16x8 ov;
#pragma unroll
  for (int c = 0; c < 8; ++c) ov[c] = f2b(o[c]);
  *(u16x8*)(attn + base + (size_t)qi * 512 + kj * 8) = ov;
}

// ---------------------------------------------------------------------------
// Build pvT[bh][n=t*64+d][w2] = attn[b][8*w2+t+1][h*64+d]  (bf16)
// ---------------------------------------------------------------------------
__global__ __launch_bounds__(256) void pvt_build(const u16* attn, u16* pvT)
{
  const int bh = blockIdx.x;
  const int b = bh >> 3, h = bh & 7;
  const int w0 = blockIdx.y * 32;
  __shared__ u16 TL[448 * 40];
  const int tid = threadIdx.x;
#pragma unroll
  for (int it = 0; it < 8; ++it) {
    int L = it * 256 + tid;
    int dg = L & 7, r = L >> 3;
    int w2l = r >> 3, tt = r & 7;
    if (tt < 7) {
      int m = 8 * (w0 + w2l) + tt + 1;
      u16x8 v = *(const u16x8*)(attn + ((size_t)b * 4096 + m) * 512 + h * 64 + dg * 8);
#pragma unroll
      for (int e = 0; e < 8; ++e)
        TL[(tt * 64 + dg * 8 + e) * 40 + w2l] = v[e];
    }
  }
  __syncthreads();
#pragma unroll
  for (int it = 0; it < 7; ++it) {
    int L = it * 256 + tid;
    int n = L >> 2, seg = L & 3;
    u16x8 v = *(const u16x8*)(&TL[n * 40 + seg * 8]);
    *(u16x8*)(pvT + ((size_t)bh * 448 + n) * 512 + w0 + seg * 8) = v;
  }
}

// ---------------------------------------------------------------------------
// LayerNorm + exact GELU on window token 0 (bf16 in/out). One wave per row.
// ---------------------------------------------------------------------------
__global__ __launch_bounds__(64) void ln_gelu(
    const u16* attn, const float* g, const float* be, u16* wt)
{
  const int r = blockIdx.x;            // r = b*512 + w
  const int b = r >> 9, w = r & 511;
  const int t = threadIdx.x;
  const u16* x = attn + (((size_t)b * 4096) + (size_t)w * 8) * 512;

  u16x8 v = *(const u16x8*)(x + t * 8);
  float xv[8];
  float s1 = 0.f, s2 = 0.f;
#pragma unroll
  for (int e = 0; e < 8; ++e) {
    xv[e] = b2f(v[e]);
    s1 += xv[e]; s2 += xv[e] * xv[e];
  }
#pragma unroll
  for (int off = 1; off < 64; off <<= 1) {
    s1 += __shfl_xor(s1, off);
    s2 += __shfl_xor(s2, off);
  }
  const float mu  = s1 * (1.0f / 512.0f);
  const float var = s2 * (1.0f / 512.0f) - mu * mu;
  const float inv = 1.0f / sqrtf(var + EPS_);

  const int d0 = t * 8;
  float4 g0 = *reinterpret_cast<const float4*>(g + d0);
  float4 g1 = *reinterpret_cast<const float4*>(g + d0 + 4);
  float4 b0 = *reinterpret_cast<const float4*>(be + d0);
  float4 b1 = *reinterpret_cast<const float4*>(be + d0 + 4);
  float gv[8] = {g0.x, g0.y, g0.z, g0.w, g1.x, g1.y, g1.z, g1.w};
  float bvv[8] = {b0.x, b0.y, b0.z, b0.w, b1.x, b1.y, b1.z, b1.w};
  const float k2 = 0.70710678118654752f;
  u16x8 ov;
#pragma unroll
  for (int e = 0; e < 8; ++e) {
    float y = (xv[e] - mu) * inv * gv[e] + bvv[e];
    ov[e] = f2b(0.5f * y * (1.0f + erff(y * k2)));
  }
  *(u16x8*)(wt + (size_t)r * 512 + d0) = ov;
}

// ---------------------------------------------------------------------------
// rsinv[row] = 1 / sum_k expS[row][k]  (bf16 in). 4 rows per 256-thread block.
// ---------------------------------------------------------------------------
__global__ __launch_bounds__(256) void rs_inv(const u16* expS, float* rsinv)
{
  const int row = blockIdx.x * 4 + (threadIdx.x >> 6);
  const int t = threadIdx.x & 63;
  u16x8 v = *(const u16x8*)(expS + (size_t)row * 512 + t * 8);
  float s = 0.f;
#pragma unroll
  for (int e = 0; e < 8; ++e) s += b2f(v[e]);
#pragma unroll
  for (int off = 1; off < 64; off <<= 1) s += __shfl_xor(s, off);
  if (t == 0) rsinv[row] = 1.0f / s;
}

// ---------------------------------------------------------------------------
// PV MFMA GEMM + rescale + residual. XCD-coscheduled 1-D grid (1792):
// t = x>>8, idx = x&255 -> all 7 t sharing an expS panel have wgid==idx mod 8
// -> same XCD -> expS re-reads are L2 hits.
// ---------------------------------------------------------------------------
__global__ __launch_bounds__(256) void pv_mfma(
    const u16* __restrict__ expS, const u16* __restrict__ pvT,
    const float* __restrict__ rsinv, const u16* __restrict__ attn,
    u16* __restrict__ X2)
{
  __shared__ u16 As[8192];   // 128 x 64
  __shared__ u16 Bs[4096];   // 64 x 64
  const int tid = threadIdx.x;
  const int lane = tid & 63, wid = tid >> 6;
  const int wr = wid >> 1, wc = wid & 1;
  const int l15 = lane & 15, lh = lane >> 4, l7 = lane & 7;
  const int nt  = blockIdx.x >> 8;            // t in [0,7)
  const int idx = blockIdx.x & 255;
  const int m0 = (idx & 3) * 128;
  const int bh = idx >> 2, b = bh >> 3, h = bh & 7;

  const f32x4 fz = {0.f, 0.f, 0.f, 0.f};
  f32x4 acc[4][2];
#pragma unroll
  for (int m = 0; m < 4; ++m)
#pragma unroll
    for (int n = 0; n < 2; ++n) acc[m][n] = fz;

  int aoff[2], boff[2];
#pragma unroll
  for (int kh = 0; kh < 2; ++kh) {
    int slot = ((kh * 4 + lh) ^ l7) << 4;
    aoff[kh] = (wr * 64 + l15) * 128 + slot;
    boff[kh] = (wc * 32 + l15) * 128 + slot;
  }

  for (int k0 = 0; k0 < 512; k0 += 64) {
    __syncthreads();
#pragma unroll
    for (int it = 0; it < 4; ++it) {
      int L = it * 256 + tid;
      int r = L >> 3, s = L & 7;
      int c = s ^ (r & 7);
      gload_lds16(expS + ((size_t)bh * 512 + m0 + r) * 512 + k0 + c * 8,
                  (char*)As + (it * 256 + wid * 64) * 16);
    }
#pragma unroll
    for (int it = 0; it < 2; ++it) {
      int L = it * 256 + tid;
      int r = L >> 3, s = L & 7;
      int c = s ^ (r & 7);
      gload_lds16(pvT + ((size_t)bh * 448 + nt * 64 + r) * 512 + k0 + c * 8,
                  (char*)Bs + (it * 256 + wid * 64) * 16);
    }
    __syncthreads();
#pragma unroll
    for (int kh = 0; kh < 2; ++kh) {
      bf16x8 af[4], bfr[2];
#pragma unroll
      for (int m = 0; m < 4; ++m)
        af[m] = *(const bf16x8*)((const char*)As + aoff[kh] + m * 2048);
#pragma unroll
      for (int n = 0; n < 2; ++n)
        bfr[n] = *(const bf16x8*)((const char*)Bs + boff[kh] + n * 2048);
#pragma unroll
      for (int m = 0; m < 4; ++m)
#pragma unroll
        for (int n = 0; n < 2; ++n)
          acc[m][n] = __builtin_amdgcn_mfma_f32_16x16x32_bf16(af[m], bfr[n], acc[m][n], 0, 0, 0);
    }
  }

#pragma unroll
  for (int m = 0; m < 4; ++m)
#pragma unroll
    for (int reg = 0; reg < 4; ++reg) {
      int gm = m0 + wr * 64 + m * 16 + lh * 4 + reg;      // wq
      float ri = rsinv[bh * 512 + gm];
#pragma unroll
      for (int n = 0; n < 2; ++n) {
        int d = wc * 32 + n * 16 + l15;
        float res = b2f(attn[((size_t)b * 4096 + gm * 8 + nt + 1) * 512 + h * 64 + d]);
        X2[((size_t)b * 3584 + gm * 7 + nt) * 512 + h * 64 + d] =
            f2b(acc[m][n][reg] * ri + res);
      }
    }
}

// ---------------------------------------------------------------------------
extern "C" void kernel_launch(void* const* d_in, const int* in_sizes, int n_in,
                              void* d_out, int out_size, void* d_ws, size_t ws_size,
                              hipStream_t stream)
{
  const float* k_in = (const float*)d_in[0];
  const float* v_in = (const float*)d_in[1];
  const float* q_in = (const float*)d_in[2];
  const float* Wk  = (const float*)d_in[4];
  const float* bk  = (const float*)d_in[5];
  const float* Wv  = (const float*)d_in[6];
  const float* bv  = (const float*)d_in[7];
  const float* Wq  = (const float*)d_in[8];
  const float* bq  = (const float*)d_in[9];
  const float* lng = (const float*)d_in[10];
  const float* lnb = (const float*)d_in[11];
  const float* Wpq = (const float*)d_in[12];
  const float* bpq = (const float*)d_in[13];
  const float* Wpk = (const float*)d_in[14];
  const float* bpk = (const float*)d_in[15];
  const float* Wo  = (const float*)d_in[16];
  const float* bo  = (const float*)d_in[17];
  float* out = (float*)d_out;

  char* ws = (char*)d_ws;
  const size_t MB = 1024 * 1024;
  u16* wtb  = (u16*)(ws);                 // 6 x 512KB transposed bf16 weights
  u16* kp   = (u16*)(ws + 16 * MB);
  u16* vp   = (u16*)(ws + 52 * MB);
  u16* qp0  = (u16*)(ws + 88 * MB);
  u16* attn = (u16*)(ws + 124 * MB);
  // phase 2 (kp/vp/qp0 regions reused after attn_win)
  u16*   wt    = (u16*)(ws + 16 * MB);
  u16*   pq    = (u16*)(ws + 20 * MB);
  u16*   pk    = (u16*)(ws + 28 * MB);
  float* rsinv = (float*)(ws + 36 * MB);
  u16*   expS  = (u16*)(ws + 40 * MB);
  u16*   pvT   = (u16*)(ws + 76 * MB);
  u16*   X2    = (u16*)(ws + 160 * MB);

  u16* Wkt  = wtb;
  u16* Wvt  = wtb + 1 * 262144;
  u16* Wqt  = wtb + 2 * 262144;
  u16* Wpqt = wtb + 3 * 262144;
  u16* Wpkt = wtb + 4 * 262144;
  u16* Wot  = wtb + 5 * 262144;

  wconv<<<dim3(8, 8, 6), 256, 0, stream>>>(Wk, Wv, Wq, Wpq, Wpk, Wo, wtb);

  gemm_proj<<<dim3(256, 1, 3), 512, 0, stream>>>(
      k_in, Wkt, bk, kp,
      v_in, Wvt, bv, vp,
      q_in, Wqt, bq, qp0);

  attn_win<<<dim3(2, 512, 8), 256, 0, stream>>>(kp, vp, qp0, attn);
  pvt_build<<<dim3(64, 16), 256, 0, stream>>>(attn, pvT);
  ln_gelu<<<4096, 64, 0, stream>>>(attn, lng, lnb, wt);

  gemm_pp<<<dim3(32, 4, 2), 256, 0, stream>>>(
      wt, Wpqt, bpq, pq, Wpkt, bpk, pk);

  qk_mfma<<<1024, 256, 0, stream>>>(pq, pk, expS);
  rs_inv<<<8192, 256, 0, stream>>>(expS, rsinv);
  pv_mfma<<<1792, 256, 0, stream>>>(expS, pvT, rsinv, attn, X2);

  gemm_out<<<dim3(224, 1, 1), 512, 0, stream>>>(X2, Wot, bo, out);
}

// Round 9
// 277.960 us; speedup vs baseline: 1.3791x; 1.0363x over previous
//
#include <hip/hip_runtime.h>
#include <hip/hip_bf16.h>
#include <math.h>

#define SCALE_ 0.04419417382415922f   // 512^-0.5
#define EPS_  1e-5f

typedef unsigned short u16;
typedef __attribute__((ext_vector_type(8))) short     bf16x8;
typedef __attribute__((ext_vector_type(4))) float     f32x4;
typedef __attribute__((ext_vector_type(8))) unsigned short u16x8;
typedef __attribute__((ext_vector_type(4))) unsigned short u16x4;

__device__ __forceinline__ u16 f2b(float f) {
  union { float f; unsigned int u; } x; x.f = f;
  unsigned int u = x.u;
  return (u16)((u + 0x7FFFu + ((u >> 16) & 1u)) >> 16);
}
__device__ __forceinline__ float b2f(u16 h) {
  union { unsigned int u; float f; } x; x.u = ((unsigned int)h) << 16;
  return x.f;
}
__device__ __forceinline__ void gload_lds16(const void* g, void* l) {
  __builtin_amdgcn_global_load_lds(
      (const __attribute__((address_space(1))) void*)g,
      (__attribute__((address_space(3))) void*)l, 16, 0, 0);
}

// ---------------------------------------------------------------------------
// Weight convert+transpose: Wt[n][k] = bf16(W[k][n]), 512x512, z selects weight
// ---------------------------------------------------------------------------
__global__ __launch_bounds__(256) void wconv(
    const float* W0, const float* W1, const float* W2,
    const float* W3, const float* W4, const float* W5, u16* wt)
{
  const float* W;
  switch (blockIdx.z) {
    case 0: W = W0; break; case 1: W = W1; break; case 2: W = W2; break;
    case 3: W = W3; break; case 4: W = W4; break; default: W = W5; break;
  }
  u16* Wt = wt + (size_t)blockIdx.z * 262144;
  const int k0 = blockIdx.x * 64, n0 = blockIdx.y * 64;
  __shared__ float T[64][68];
  const int tid = threadIdx.x;
#pragma unroll
  for (int it = 0; it < 4; ++it) {
    int L = it * 256 + tid;
    int r = L >> 4, cg = L & 15;
    float4 v = *reinterpret_cast<const float4*>(W + (size_t)(k0 + r) * 512 + n0 + cg * 4);
    T[r][cg * 4 + 0] = v.x; T[r][cg * 4 + 1] = v.y;
    T[r][cg * 4 + 2] = v.z; T[r][cg * 4 + 3] = v.w;
  }
  __syncthreads();
#pragma unroll
  for (int it = 0; it < 2; ++it) {
    int L = it * 256 + tid;
    int rn = L >> 3, kg = L & 7;
    u16x8 o;
#pragma unroll
    for (int e = 0; e < 8; ++e) o[e] = f2b(T[kg * 8 + e][rn]);
    *(u16x8*)(Wt + (size_t)(n0 + rn) * 512 + k0 + kg * 8) = o;
  }
}

// ---------------------------------------------------------------------------
// Strip projection GEMM (proven ~120us): full-N strip, BK=64,
// C_bf16[128 x 512] = bf16(A_f32) @ Bt^T + bias. 512 thr = 8 waves (2Mx4N).
// ---------------------------------------------------------------------------
__global__ __launch_bounds__(512) void gemm_proj(
    const float* A0, const u16* Bt0, const float* bi0, u16* C0,
    const float* A1, const u16* Bt1, const float* bi1, u16* C1,
    const float* A2, const u16* Bt2, const float* bi2, u16* C2)
{
  const float *A, *bias; const u16* Bt; u16* C;
  if (blockIdx.z == 0)      { A = A0; Bt = Bt0; bias = bi0; C = C0; }
  else if (blockIdx.z == 1) { A = A1; Bt = Bt1; bias = bi1; C = C1; }
  else                      { A = A2; Bt = Bt2; bias = bi2; C = C2; }

  __shared__ u16 As[8192];    // 128 rows x 64 k
  __shared__ u16 Bs[32768];   // 512 n-rows x 64 k
  const int tid = threadIdx.x;
  const int lane = tid & 63, wid = tid >> 6;
  const int wr = wid >> 2, wcn = wid & 3;          // 2 x 4 wave grid
  const int l15 = lane & 15, lh = lane >> 4, l7 = lane & 7;
  const int m0 = blockIdx.x * 128;

  const f32x4 fz = {0.f, 0.f, 0.f, 0.f};
  f32x4 acc[4][8];
#pragma unroll
  for (int m = 0; m < 4; ++m)
#pragma unroll
    for (int n = 0; n < 8; ++n) acc[m][n] = fz;

  int aoff[2], boff[2];
#pragma unroll
  for (int kh = 0; kh < 2; ++kh) {
    int slot = ((kh * 4 + lh) ^ l7) << 4;
    aoff[kh] = (wr * 64 + l15) * 128 + slot;
    boff[kh] = (wcn * 128 + l15) * 128 + slot;
  }

  for (int k0 = 0; k0 < 512; k0 += 64) {
    __syncthreads();
#pragma unroll
    for (int it = 0; it < 8; ++it) {
      int L = it * 512 + tid;
      int r = L >> 3, s = L & 7;
      int c = s ^ (r & 7);
      gload_lds16(Bt + (size_t)r * 512 + k0 + c * 8,
                  (char*)Bs + (it * 512 + wid * 64) * 16);
    }
    float4 xa[2], xb[2];
#pragma unroll
    for (int it = 0; it < 2; ++it) {
      int L = it * 512 + tid;
      int r = L >> 3, s = L & 7;
      int c = s ^ (r & 7);
      const float* ga = A + (size_t)(m0 + r) * 512 + k0 + c * 8;
      xa[it] = *reinterpret_cast<const float4*>(ga);
      xb[it] = *reinterpret_cast<const float4*>(ga + 4);
    }
#pragma unroll
    for (int it = 0; it < 2; ++it) {
      int L = it * 512 + tid;
      u16x8 o;
      o[0] = f2b(xa[it].x); o[1] = f2b(xa[it].y);
      o[2] = f2b(xa[it].z); o[3] = f2b(xa[it].w);
      o[4] = f2b(xb[it].x); o[5] = f2b(xb[it].y);
      o[6] = f2b(xb[it].z); o[7] = f2b(xb[it].w);
      *(u16x8*)((char*)As + L * 16) = o;
    }
    __syncthreads();
#pragma unroll
    for (int kh = 0; kh < 2; ++kh) {
      bf16x8 af[4], bfr[8];
#pragma unroll
      for (int m = 0; m < 4; ++m)
        af[m] = *(const bf16x8*)((const char*)As + aoff[kh] + m * 2048);
#pragma unroll
      for (int n = 0; n < 8; ++n)
        bfr[n] = *(const bf16x8*)((const char*)Bs + boff[kh] + n * 2048);
#pragma unroll
      for (int m = 0; m < 4; ++m)
#pragma unroll
        for (int n = 0; n < 8; ++n)
          acc[m][n] = __builtin_amdgcn_mfma_f32_16x16x32_bf16(af[m], bfr[n], acc[m][n], 0, 0, 0);
    }
  }

  const int gn0 = wcn * 128 + l15;
  float bv[8];
#pragma unroll
  for (int n = 0; n < 8; ++n) bv[n] = bias[gn0 + n * 16];
#pragma unroll
  for (int m = 0; m < 4; ++m)
#pragma unroll
    for (int reg = 0; reg < 4; ++reg) {
      int gm = m0 + wr * 64 + m * 16 + lh * 4 + reg;
#pragma unroll
      for (int n = 0; n < 8; ++n)
        C[(size_t)gm * 512 + gn0 + n * 16] = f2b(acc[m][n][reg] + bv[n]);
    }
}

// ---------------------------------------------------------------------------
// Strip output GEMM, double-buffered: out_f32 = A_bf16 @ Bt^T + bias.
// ---------------------------------------------------------------------------
__global__ __launch_bounds__(512) void gemm_out(
    const u16* __restrict__ A, const u16* __restrict__ Bt,
    const float* __restrict__ bias, float* __restrict__ C)
{
  __shared__ u16 As[2][4096];
  __shared__ u16 Bs[2][16384];
  const int tid = threadIdx.x;
  const int lane = tid & 63, wid = tid >> 6;
  const int wr = wid >> 2, wcn = wid & 3;
  const int l15 = lane & 15, lh = lane >> 4;
  const int sx = (l15 >> 1) & 3;
  const int m0 = blockIdx.x * 128;
  const int rr = tid >> 2, sp = tid & 3;
  const int ssw = sp ^ ((rr >> 1) & 3);

  const f32x4 fz = {0.f, 0.f, 0.f, 0.f};
  f32x4 acc[4][8];
#pragma unroll
  for (int m = 0; m < 4; ++m)
#pragma unroll
    for (int n = 0; n < 8; ++n) acc[m][n] = fz;

  const int aoff0 = (wr * 64 + l15) * 64 + ((lh ^ sx) << 4);
  const int boff0 = (wcn * 128 + l15) * 64 + ((lh ^ sx) << 4);

  {
#pragma unroll
    for (int it = 0; it < 4; ++it)
      gload_lds16(Bt + (size_t)(it * 128 + rr) * 512 + ssw * 8,
                  (char*)Bs[0] + (it * 512 + wid * 64) * 16);
    gload_lds16(A + (size_t)(m0 + rr) * 512 + ssw * 8,
                (char*)As[0] + (wid * 64) * 16);
  }
  __syncthreads();

#pragma unroll 2
  for (int t = 0; t < 16; ++t) {
    const int cur = t & 1, nxt = cur ^ 1;
    if (t < 15) {
      const int k0 = (t + 1) * 32;
#pragma unroll
      for (int it = 0; it < 4; ++it)
        gload_lds16(Bt + (size_t)(it * 128 + rr) * 512 + k0 + ssw * 8,
                    (char*)Bs[nxt] + (it * 512 + wid * 64) * 16);
      gload_lds16(A + (size_t)(m0 + rr) * 512 + k0 + ssw * 8,
                  (char*)As[nxt] + (wid * 64) * 16);
    }
    bf16x8 af[4], bfr[8];
#pragma unroll
    for (int m = 0; m < 4; ++m)
      af[m] = *(const bf16x8*)((const char*)As[cur] + aoff0 + m * 1024);
#pragma unroll
    for (int n = 0; n < 8; ++n)
      bfr[n] = *(const bf16x8*)((const char*)Bs[cur] + boff0 + n * 1024);
#pragma unroll
    for (int m = 0; m < 4; ++m)
#pragma unroll
      for (int n = 0; n < 8; ++n)
        acc[m][n] = __builtin_amdgcn_mfma_f32_16x16x32_bf16(af[m], bfr[n], acc[m][n], 0, 0, 0);
    __syncthreads();
  }

  const int gn0 = wcn * 128 + l15;
  float bv[8];
#pragma unroll
  for (int n = 0; n < 8; ++n) bv[n] = bias[gn0 + n * 16];
#pragma unroll
  for (int m = 0; m < 4; ++m)
#pragma unroll
    for (int reg = 0; reg < 4; ++reg) {
      int gm = m0 + wr * 64 + m * 16 + lh * 4 + reg;
#pragma unroll
      for (int n = 0; n < 8; ++n)
        C[(size_t)gm * 512 + gn0 + n * 16] = acc[m][n][reg] + bv[n];
    }
}

// ---------------------------------------------------------------------------
// pq/pk GEMM (small): bf16 out. 128x128 tiles, z selects set. Bt is [n][k].
// ---------------------------------------------------------------------------
__global__ __launch_bounds__(256) void gemm_pp(
    const u16* __restrict__ A,
    const u16* __restrict__ Bt0, const float* __restrict__ bi0, u16* __restrict__ C0,
    const u16* __restrict__ Bt1, const float* __restrict__ bi1, u16* __restrict__ C1)
{
  const u16* Bt; const float* bias; u16* C;
  if (blockIdx.z == 0) { Bt = Bt0; bias = bi0; C = C0; }
  else                 { Bt = Bt1; bias = bi1; C = C1; }

  __shared__ u16 As[8192];   // 128 x 64
  __shared__ u16 Bs[8192];   // 128 x 64
  const int tid = threadIdx.x;
  const int lane = tid & 63, wid = tid >> 6;
  const int wr = wid >> 1, wc = wid & 1;
  const int l15 = lane & 15, lh = lane >> 4, l7 = lane & 7;
  const int m0 = blockIdx.x * 128, n0 = blockIdx.y * 128;

  const f32x4 fz = {0.f, 0.f, 0.f, 0.f};
  f32x4 acc[4][4];
#pragma unroll
  for (int m = 0; m < 4; ++m)
#pragma unroll
    for (int n = 0; n < 4; ++n) acc[m][n] = fz;

  int aoff[2], boff[2];
#pragma unroll
  for (int kh = 0; kh < 2; ++kh) {
    int slot = ((kh * 4 + lh) ^ l7) << 4;
    aoff[kh] = (wr * 64 + l15) * 128 + slot;
    boff[kh] = (wc * 64 + l15) * 128 + slot;
  }

  for (int k0 = 0; k0 < 512; k0 += 64) {
    __syncthreads();
#pragma unroll
    for (int it = 0; it < 4; ++it) {
      int L = it * 256 + tid;
      int r = L >> 3, s = L & 7;
      int c = s ^ (r & 7);
      gload_lds16(A  + (size_t)(m0 + r) * 512 + k0 + c * 8,
                  (char*)As + (it * 256 + wid * 64) * 16);
      gload_lds16(Bt + (size_t)(n0 + r) * 512 + k0 + c * 8,
                  (char*)Bs + (it * 256 + wid * 64) * 16);
    }
    __syncthreads();
#pragma unroll
    for (int kh = 0; kh < 2; ++kh) {
      bf16x8 af[4], bfr[4];
#pragma unroll
      for (int m = 0; m < 4; ++m)
        af[m] = *(const bf16x8*)((const char*)As + aoff[kh] + m * 2048);
#pragma unroll
      for (int n = 0; n < 4; ++n)
        bfr[n] = *(const bf16x8*)((const char*)Bs + boff[kh] + n * 2048);
#pragma unroll
      for (int m = 0; m < 4; ++m)
#pragma unroll
        for (int n = 0; n < 4; ++n)
          acc[m][n] = __builtin_amdgcn_mfma_f32_16x16x32_bf16(af[m], bfr[n], acc[m][n], 0, 0, 0);
    }
  }

  const int gn0 = n0 + wc * 64 + l15;
  float bv[4];
#pragma unroll
  for (int n = 0; n < 4; ++n) bv[n] = bias[gn0 + n * 16];
#pragma unroll
  for (int m = 0; m < 4; ++m)
#pragma unroll
    for (int reg = 0; reg < 4; ++reg) {
      int gm = m0 + wr * 64 + m * 16 + lh * 4 + reg;
#pragma unroll
      for (int n = 0; n < 4; ++n)
        C[(size_t)gm * 512 + gn0 + n * 16] = f2b(acc[m][n][reg] + bv[n]);
    }
}

// ---------------------------------------------------------------------------
// qk_mfma: expS = exp(SCALE * pq . pk) via MFMA, PLUS fused partial row sums:
// rsumP[bh][p][wq], p = (wk0>>6)+wc in 0..7 (f32, exact exp values).
// XCD-coscheduled 1-D grid: same bh -> same XCD.
// ---------------------------------------------------------------------------
__global__ __launch_bounds__(256) void qk_mfma(
    const u16* __restrict__ pq, const u16* __restrict__ pk,
    u16* __restrict__ expS, float* __restrict__ rsumP)
{
  __shared__ u16 As[8192];   // 128 x 64
  __shared__ u16 Bs[8192];
  const int tid = threadIdx.x;
  const int lane = tid & 63, wid = tid >> 6;
  const int wr = wid >> 1, wc = wid & 1;
  const int l15 = lane & 15, lh = lane >> 4, l7 = lane & 7;
  const int bh = blockIdx.x & 63;
  const int sidx = blockIdx.x >> 6;                 // 0..15
  const int b = bh >> 3, h = bh & 7;
  const int wq0 = (sidx & 3) * 128, wk0 = (sidx >> 2) * 128;

  const f32x4 fz = {0.f, 0.f, 0.f, 0.f};
  f32x4 acc[4][4];
#pragma unroll
  for (int m = 0; m < 4; ++m)
#pragma unroll
    for (int n = 0; n < 4; ++n) acc[m][n] = fz;

#pragma unroll
  for (int it = 0; it < 4; ++it) {
    int L = it * 256 + tid;
    int r = L >> 3, s = L & 7;
    int c = s ^ (r & 7);
    gload_lds16(pq + ((size_t)b * 512 + wq0 + r) * 512 + h * 64 + c * 8,
                (char*)As + (it * 256 + wid * 64) * 16);
    gload_lds16(pk + ((size_t)b * 512 + wk0 + r) * 512 + h * 64 + c * 8,
                (char*)Bs + (it * 256 + wid * 64) * 16);
  }
  __syncthreads();

#pragma unroll
  for (int kh = 0; kh < 2; ++kh) {
    int slot = ((kh * 4 + lh) ^ l7) << 4;
    int aoff = (wr * 64 + l15) * 128 + slot;
    int boff = (wc * 64 + l15) * 128 + slot;
    bf16x8 af[4], bfr[4];
#pragma unroll
    for (int m = 0; m < 4; ++m)
      af[m] = *(const bf16x8*)((const char*)As + aoff + m * 2048);
#pragma unroll
    for (int n = 0; n < 4; ++n)
      bfr[n] = *(const bf16x8*)((const char*)Bs + boff + n * 2048);
#pragma unroll
    for (int m = 0; m < 4; ++m)
#pragma unroll
      for (int n = 0; n < 4; ++n)
        acc[m][n] = __builtin_amdgcn_mfma_f32_16x16x32_bf16(af[m], bfr[n], acc[m][n], 0, 0, 0);
  }

  const int gn0 = wk0 + wc * 64 + l15;
  float rs[4][4];
#pragma unroll
  for (int m = 0; m < 4; ++m)
#pragma unroll
    for (int reg = 0; reg < 4; ++reg) {
      int gm = wq0 + wr * 64 + m * 16 + lh * 4 + reg;
      float rsum = 0.0f;
#pragma unroll
      for (int n = 0; n < 4; ++n) {
        float e = expf(acc[m][n][reg] * SCALE_);
        rsum += e;
        expS[((size_t)bh * 512 + gm) * 512 + gn0 + n * 16] = f2b(e);
      }
      rs[m][reg] = rsum;
    }

  // reduce over the 16-lane l15 group (lanes differ only in bits 0..3)
#pragma unroll
  for (int m = 0; m < 4; ++m)
#pragma unroll
    for (int reg = 0; reg < 4; ++reg) {
      float v = rs[m][reg];
      v += __shfl_xor(v, 1);
      v += __shfl_xor(v, 2);
      v += __shfl_xor(v, 4);
      v += __shfl_xor(v, 8);
      rs[m][reg] = v;
    }
  if (l15 == 0) {
    const int p = (wk0 >> 6) + wc;          // 0..7
#pragma unroll
    for (int m = 0; m < 4; ++m)
#pragma unroll
      for (int reg = 0; reg < 4; ++reg) {
        int gm = wq0 + wr * 64 + m * 16 + lh * 4 + reg;
        rsumP[((size_t)bh * 8 + p) * 512 + gm] = rs[m][reg];
      }
  }
}

// ---------------------------------------------------------------------------
// Window attention (bf16 in/out), fused q 5-tap smoothing. fp32 math.
// One 64-thread block per (h, w, b).  [round-5 proven config]
// ---------------------------------------------------------------------------
__global__ __launch_bounds__(64) void attn_win(
    const u16* kp, const u16* vp, const u16* qp0, u16* attn)
{
  const int h = blockIdx.x, w = blockIdx.y, b = blockIdx.z;
  const int t = threadIdx.x;
  __shared__ float ks[8][68], vs[8][68], qr[12][68], qs[8][68], Ps[8][9];
  const size_t base = ((size_t)b * 4096 + (size_t)w * 8) * 512 + h * 64;

  {
    int i = t >> 3, dg = t & 7;
    u16x8 kv = *(const u16x8*)(kp + base + (size_t)i * 512 + dg * 8);
    u16x8 vv = *(const u16x8*)(vp + base + (size_t)i * 512 + dg * 8);
#pragma unroll
    for (int e = 0; e < 8; ++e) {
      ks[i][dg * 8 + e] = b2f(kv[e]);
      vs[i][dg * 8 + e] = b2f(vv[e]);
    }
  }
#pragma unroll
  for (int l = 0; l < 2; ++l) {
    int L = t + l * 64;
    if (L < 96) {
      int i = L >> 3, dg = L & 7;
      int m = w * 8 - 2 + i;
      if (m >= 0 && m < 4096) {
        u16x8 qv = *(const u16x8*)(qp0 + ((size_t)b * 4096 + m) * 512 + h * 64 + dg * 8);
#pragma unroll
        for (int e = 0; e < 8; ++e) qr[i][dg * 8 + e] = b2f(qv[e]);
      } else {
#pragma unroll
        for (int e = 0; e < 8; ++e) qr[i][dg * 8 + e] = 0.0f;
      }
    }
  }
  __syncthreads();
#pragma unroll
  for (int j = 0; j < 8; ++j)
    qs[j][t] = 0.2f * (qr[j][t] + qr[j + 1][t] + qr[j + 2][t] + qr[j + 3][t] + qr[j + 4][t]);
  __syncthreads();

  const int qi = t >> 3, kj = t & 7;
  float s = 0.0f;
#pragma unroll
  for (int d = 0; d < 64; ++d) s = fmaf(qs[qi][d], ks[kj][d], s);
  s *= SCALE_;
  float mx = s;
  mx = fmaxf(mx, __shfl_xor(mx, 1));
  mx = fmaxf(mx, __shfl_xor(mx, 2));
  mx = fmaxf(mx, __shfl_xor(mx, 4));
  float e = expf(s - mx);
  float sum = e;
  sum += __shfl_xor(sum, 1);
  sum += __shfl_xor(sum, 2);
  sum += __shfl_xor(sum, 4);
  Ps[qi][kj] = e / sum;
  __syncthreads();

  float o[8];
#pragma unroll
  for (int c = 0; c < 8; ++c) o[c] = 0.0f;
#pragma unroll
  for (int tt = 0; tt < 8; ++tt) {
    float pw = Ps[qi][tt];
#pragma unroll
    for (int c = 0; c < 8; ++c) o[c] = fmaf(pw, vs[tt][kj * 8 + c], o[c]);
  }
  u16x8 ov;
#pragma unroll
  for (int c = 0; c < 8; ++c) ov[c] = f2b(o[c]);
  *(u16x8*)(attn + base + (size_t)qi * 512 + kj * 8) = ov;
}

// ---------------------------------------------------------------------------
// Build pvT[bh][n=t*64+d][w2] = attn[b][8*w2+t+1][h*64+d]  (bf16)
// ---------------------------------------------------------------------------
__global__ __launch_bounds__(256) void pvt_build(const u16* attn, u16* pvT)
{
  const int bh = blockIdx.x;
  const int b = bh >> 3, h = bh & 7;
  const int w0 = blockIdx.y * 32;
  __shared__ u16 TL[448 * 40];
  const int tid = threadIdx.x;
#pragma unroll
  for (int it = 0; it < 8; ++it) {
    int L = it * 256 + tid;
    int dg = L & 7, r = L >> 3;
    int w2l = r >> 3, tt = r & 7;
    if (tt < 7) {
      int m = 8 * (w0 + w2l) + tt + 1;
      u16x8 v = *(const u16x8*)(attn + ((size_t)b * 4096 + m) * 512 + h * 64 + dg * 8);
#pragma unroll
      for (int e = 0; e < 8; ++e)
        TL[(tt * 64 + dg * 8 + e) * 40 + w2l] = v[e];
    }
  }
  __syncthreads();
#pragma unroll
  for (int it = 0; it < 7; ++it) {
    int L = it * 256 + tid;
    int n = L >> 2, seg = L & 3;
    u16x8 v = *(const u16x8*)(&TL[n * 40 + seg * 8]);
    *(u16x8*)(pvT + ((size_t)bh * 448 + n) * 512 + w0 + seg * 8) = v;
  }
}

// ---------------------------------------------------------------------------
// LayerNorm + exact GELU on window token 0 (bf16 in/out). One wave per row.
// ---------------------------------------------------------------------------
__global__ __launch_bounds__(64) void ln_gelu(
    const u16* attn, const float* g, const float* be, u16* wt)
{
  const int r = blockIdx.x;            // r = b*512 + w
  const int b = r >> 9, w = r & 511;
  const int t = threadIdx.x;
  const u16* x = attn + (((size_t)b * 4096) + (size_t)w * 8) * 512;

  u16x8 v = *(const u16x8*)(x + t * 8);
  float xv[8];
  float s1 = 0.f, s2 = 0.f;
#pragma unroll
  for (int e = 0; e < 8; ++e) {
    xv[e] = b2f(v[e]);
    s1 += xv[e]; s2 += xv[e] * xv[e];
  }
#pragma unroll
  for (int off = 1; off < 64; off <<= 1) {
    s1 += __shfl_xor(s1, off);
    s2 += __shfl_xor(s2, off);
  }
  const float mu  = s1 * (1.0f / 512.0f);
  const float var = s2 * (1.0f / 512.0f) - mu * mu;
  const float inv = 1.0f / sqrtf(var + EPS_);

  const int d0 = t * 8;
  float4 g0 = *reinterpret_cast<const float4*>(g + d0);
  float4 g1 = *reinterpret_cast<const float4*>(g + d0 + 4);
  float4 b0 = *reinterpret_cast<const float4*>(be + d0);
  float4 b1 = *reinterpret_cast<const float4*>(be + d0 + 4);
  float gv[8] = {g0.x, g0.y, g0.z, g0.w, g1.x, g1.y, g1.z, g1.w};
  float bvv[8] = {b0.x, b0.y, b0.z, b0.w, b1.x, b1.y, b1.z, b1.w};
  const float k2 = 0.70710678118654752f;
  u16x8 ov;
#pragma unroll
  for (int e = 0; e < 8; ++e) {
    float y = (xv[e] - mu) * inv * gv[e] + bvv[e];
    ov[e] = f2b(0.5f * y * (1.0f + erff(y * k2)));
  }
  *(u16x8*)(wt + (size_t)r * 512 + d0) = ov;
}

// ---------------------------------------------------------------------------
// rsinv[row] = 1 / sum_p rsumP[bh][p][wq]  (8 f32 partials per row)
// ---------------------------------------------------------------------------
__global__ __launch_bounds__(256) void rs_inv(const float* rsumP, float* rsinv)
{
  const int row = blockIdx.x * 256 + threadIdx.x;   // row = bh*512 + wq
  const int bh = row >> 9, wq = row & 511;
  float s = 0.f;
#pragma unroll
  for (int p = 0; p < 8; ++p)
    s += rsumP[((size_t)bh * 8 + p) * 512 + wq];
  rsinv[row] = 1.0f / s;
}

// ---------------------------------------------------------------------------
// PV MFMA GEMM + rescale + residual. XCD-coscheduled 1-D grid (1792):
// t = x>>8, idx = x&255 -> all 7 t sharing an expS panel co-XCD.
// ---------------------------------------------------------------------------
__global__ __launch_bounds__(256) void pv_mfma(
    const u16* __restrict__ expS, const u16* __restrict__ pvT,
    const float* __restrict__ rsinv, const u16* __restrict__ attn,
    u16* __restrict__ X2)
{
  __shared__ u16 As[8192];   // 128 x 64
  __shared__ u16 Bs[4096];   // 64 x 64
  const int tid = threadIdx.x;
  const int lane = tid & 63, wid = tid >> 6;
  const int wr = wid >> 1, wc = wid & 1;
  const int l15 = lane & 15, lh = lane >> 4, l7 = lane & 7;
  const int nt  = blockIdx.x >> 8;            // t in [0,7)
  const int idx = blockIdx.x & 255;
  const int m0 = (idx & 3) * 128;
  const int bh = idx >> 2, b = bh >> 3, h = bh & 7;

  const f32x4 fz = {0.f, 0.f, 0.f, 0.f};
  f32x4 acc[4][2];
#pragma unroll
  for (int m = 0; m < 4; ++m)
#pragma unroll
    for (int n = 0; n < 2; ++n) acc[m][n] = fz;

  int aoff[2], boff[2];
#pragma unroll
  for (int kh = 0; kh < 2; ++kh) {
    int slot = ((kh * 4 + lh) ^ l7) << 4;
    aoff[kh] = (wr * 64 + l15) * 128 + slot;
    boff[kh] = (wc * 32 + l15) * 128 + slot;
  }

  for (int k0 = 0; k0 < 512; k0 += 64) {
    __syncthreads();
#pragma unroll
    for (int it = 0; it < 4; ++it) {
      int L = it * 256 + tid;
      int r = L >> 3, s = L & 7;
      int c = s ^ (r & 7);
      gload_lds16(expS + ((size_t)bh * 512 + m0 + r) * 512 + k0 + c * 8,
                  (char*)As + (it * 256 + wid * 64) * 16);
    }
#pragma unroll
    for (int it = 0; it < 2; ++it) {
      int L = it * 256 + tid;
      int r = L >> 3, s = L & 7;
      int c = s ^ (r & 7);
      gload_lds16(pvT + ((size_t)bh * 448 + nt * 64 + r) * 512 + k0 + c * 8,
                  (char*)Bs + (it * 256 + wid * 64) * 16);
    }
    __syncthreads();
#pragma unroll
    for (int kh = 0; kh < 2; ++kh) {
      bf16x8 af[4], bfr[2];
#pragma unroll
      for (int m = 0; m < 4; ++m)
        af[m] = *(const bf16x8*)((const char*)As + aoff[kh] + m * 2048);
#pragma unroll
      for (int n = 0; n < 2; ++n)
        bfr[n] = *(const bf16x8*)((const char*)Bs + boff[kh] + n * 2048);
#pragma unroll
      for (int m = 0; m < 4; ++m)
#pragma unroll
        for (int n = 0; n < 2; ++n)
          acc[m][n] = __builtin_amdgcn_mfma_f32_16x16x32_bf16(af[m], bfr[n], acc[m][n], 0, 0, 0);
    }
  }

#pragma unroll
  for (int m = 0; m < 4; ++m)
#pragma unroll
    for (int reg = 0; reg < 4; ++reg) {
      int gm = m0 + wr * 64 + m * 16 + lh * 4 + reg;      // wq
      float ri = rsinv[bh * 512 + gm];
#pragma unroll
      for (int n = 0; n < 2; ++n) {
        int d = wc * 32 + n * 16 + l15;
        float res = b2f(attn[((size_t)b * 4096 + gm * 8 + nt + 1) * 512 + h * 64 + d]);
        X2[((size_t)b * 3584 + gm * 7 + nt) * 512 + h * 64 + d] =
            f2b(acc[m][n][reg] * ri + res);
      }
    }
}

// ---------------------------------------------------------------------------
extern "C" void kernel_launch(void* const* d_in, const int* in_sizes, int n_in,
                              void* d_out, int out_size, void* d_ws, size_t ws_size,
                              hipStream_t stream)
{
  const float* k_in = (const float*)d_in[0];
  const float* v_in = (const float*)d_in[1];
  const float* q_in = (const float*)d_in[2];
  const float* Wk  = (const float*)d_in[4];
  const float* bk  = (const float*)d_in[5];
  const float* Wv  = (const float*)d_in[6];
  const float* bv  = (const float*)d_in[7];
  const float* Wq  = (const float*)d_in[8];
  const float* bq  = (const float*)d_in[9];
  const float* lng = (const float*)d_in[10];
  const float* lnb = (const float*)d_in[11];
  const float* Wpq = (const float*)d_in[12];
  const float* bpq = (const float*)d_in[13];
  const float* Wpk = (const float*)d_in[14];
  const float* bpk = (const float*)d_in[15];
  const float* Wo  = (const float*)d_in[16];
  const float* bo  = (const float*)d_in[17];
  float* out = (float*)d_out;

  char* ws = (char*)d_ws;
  const size_t MB = 1024 * 1024;
  u16* wtb  = (u16*)(ws);                 // 6 x 512KB transposed bf16 weights
  u16* kp   = (u16*)(ws + 16 * MB);
  u16* vp   = (u16*)(ws + 52 * MB);
  u16* qp0  = (u16*)(ws + 88 * MB);
  u16* attn = (u16*)(ws + 124 * MB);
  // phase 2 (kp/vp/qp0 regions reused after attn_win)
  u16*   wt    = (u16*)(ws + 16 * MB);
  u16*   pq    = (u16*)(ws + 20 * MB);
  u16*   pk    = (u16*)(ws + 28 * MB);
  float* rsinv = (float*)(ws + 36 * MB);
  float* rsumP = (float*)(ws + 37 * MB);  // 1MB: [64bh][8][512] f32
  u16*   expS  = (u16*)(ws + 40 * MB);
  u16*   pvT   = (u16*)(ws + 76 * MB);
  u16*   X2    = (u16*)(ws + 160 * MB);

  u16* Wkt  = wtb;
  u16* Wvt  = wtb + 1 * 262144;
  u16* Wqt  = wtb + 2 * 262144;
  u16* Wpqt = wtb + 3 * 262144;
  u16* Wpkt = wtb + 4 * 262144;
  u16* Wot  = wtb + 5 * 262144;

  wconv<<<dim3(8, 8, 6), 256, 0, stream>>>(Wk, Wv, Wq, Wpq, Wpk, Wo, wtb);

  gemm_proj<<<dim3(256, 1, 3), 512, 0, stream>>>(
      k_in, Wkt, bk, kp,
      v_in, Wvt, bv, vp,
      q_in, Wqt, bq, qp0);

  attn_win<<<dim3(8, 512, 8), 64, 0, stream>>>(kp, vp, qp0, attn);
  pvt_build<<<dim3(64, 16), 256, 0, stream>>>(attn, pvT);
  ln_gelu<<<4096, 64, 0, stream>>>(attn, lng, lnb, wt);

  gemm_pp<<<dim3(32, 4, 2), 256, 0, stream>>>(
      wt, Wpqt, bpq, pq, Wpkt, bpk, pk);

  qk_mfma<<<1024, 256, 0, stream>>>(pq, pk, expS, rsumP);
  rs_inv<<<128, 256, 0, stream>>>(rsumP, rsinv);
  pv_mfma<<<1792, 256, 0, stream>>>(expS, pvT, rsinv, attn, X2);

  gemm_out<<<dim3(224, 1, 1), 512, 0, stream>>>(X2, Wot, bo, out);
}

// Round 10
// 256.110 us; speedup vs baseline: 1.4967x; 1.0853x over previous
//
#include <hip/hip_runtime.h>
#include <hip/hip_bf16.h>
#include <math.h>

#define SCALE_ 0.04419417382415922f   // 512^-0.5
#define EPS_  1e-5f

typedef unsigned short u16;
typedef __attribute__((ext_vector_type(8))) short     bf16x8;
typedef __attribute__((ext_vector_type(4))) float     f32x4;
typedef __attribute__((ext_vector_type(8))) unsigned short u16x8;
typedef __attribute__((ext_vector_type(4))) unsigned short u16x4;

__device__ __forceinline__ u16 f2b(float f) {
  union { float f; unsigned int u; } x; x.f = f;
  unsigned int u = x.u;
  return (u16)((u + 0x7FFFu + ((u >> 16) & 1u)) >> 16);
}
__device__ __forceinline__ float b2f(u16 h) {
  union { unsigned int u; float f; } x; x.u = ((unsigned int)h) << 16;
  return x.f;
}
__device__ __forceinline__ void gload_lds16(const void* g, void* l) {
  __builtin_amdgcn_global_load_lds(
      (const __attribute__((address_space(1))) void*)g,
      (__attribute__((address_space(3))) void*)l, 16, 0, 0);
}

// ---------------------------------------------------------------------------
// Weight convert+transpose: Wt[n][k] = bf16(W[k][n]), 512x512, z selects weight
// ---------------------------------------------------------------------------
__global__ __launch_bounds__(256) void wconv(
    const float* W0, const float* W1, const float* W2,
    const float* W3, const float* W4, const float* W5, u16* wt)
{
  const float* W;
  switch (blockIdx.z) {
    case 0: W = W0; break; case 1: W = W1; break; case 2: W = W2; break;
    case 3: W = W3; break; case 4: W = W4; break; default: W = W5; break;
  }
  u16* Wt = wt + (size_t)blockIdx.z * 262144;
  const int k0 = blockIdx.x * 64, n0 = blockIdx.y * 64;
  __shared__ float T[64][68];
  const int tid = threadIdx.x;
#pragma unroll
  for (int it = 0; it < 4; ++it) {
    int L = it * 256 + tid;
    int r = L >> 4, cg = L & 15;
    float4 v = *reinterpret_cast<const float4*>(W + (size_t)(k0 + r) * 512 + n0 + cg * 4);
    T[r][cg * 4 + 0] = v.x; T[r][cg * 4 + 1] = v.y;
    T[r][cg * 4 + 2] = v.z; T[r][cg * 4 + 3] = v.w;
  }
  __syncthreads();
#pragma unroll
  for (int it = 0; it < 2; ++it) {
    int L = it * 256 + tid;
    int rn = L >> 3, kg = L & 7;
    u16x8 o;
#pragma unroll
    for (int e = 0; e < 8; ++e) o[e] = f2b(T[kg * 8 + e][rn]);
    *(u16x8*)(Wt + (size_t)(n0 + rn) * 512 + k0 + kg * 8) = o;
  }
}

// ---------------------------------------------------------------------------
// Strip projection GEMM (proven ~120us): full-N strip, BK=64,
// C_bf16[128 x 512] = bf16(A_f32) @ Bt^T + bias. 512 thr = 8 waves (2Mx4N).
// ---------------------------------------------------------------------------
__global__ __launch_bounds__(512) void gemm_proj(
    const float* A0, const u16* Bt0, const float* bi0, u16* C0,
    const float* A1, const u16* Bt1, const float* bi1, u16* C1,
    const float* A2, const u16* Bt2, const float* bi2, u16* C2)
{
  const float *A, *bias; const u16* Bt; u16* C;
  if (blockIdx.z == 0)      { A = A0; Bt = Bt0; bias = bi0; C = C0; }
  else if (blockIdx.z == 1) { A = A1; Bt = Bt1; bias = bi1; C = C1; }
  else                      { A = A2; Bt = Bt2; bias = bi2; C = C2; }

  __shared__ u16 As[8192];    // 128 rows x 64 k
  __shared__ u16 Bs[32768];   // 512 n-rows x 64 k
  const int tid = threadIdx.x;
  const int lane = tid & 63, wid = tid >> 6;
  const int wr = wid >> 2, wcn = wid & 3;          // 2 x 4 wave grid
  const int l15 = lane & 15, lh = lane >> 4, l7 = lane & 7;
  const int m0 = blockIdx.x * 128;

  const f32x4 fz = {0.f, 0.f, 0.f, 0.f};
  f32x4 acc[4][8];
#pragma unroll
  for (int m = 0; m < 4; ++m)
#pragma unroll
    for (int n = 0; n < 8; ++n) acc[m][n] = fz;

  int aoff[2], boff[2];
#pragma unroll
  for (int kh = 0; kh < 2; ++kh) {
    int slot = ((kh * 4 + lh) ^ l7) << 4;
    aoff[kh] = (wr * 64 + l15) * 128 + slot;
    boff[kh] = (wcn * 128 + l15) * 128 + slot;
  }

  for (int k0 = 0; k0 < 512; k0 += 64) {
    __syncthreads();
#pragma unroll
    for (int it = 0; it < 8; ++it) {
      int L = it * 512 + tid;
      int r = L >> 3, s = L & 7;
      int c = s ^ (r & 7);
      gload_lds16(Bt + (size_t)r * 512 + k0 + c * 8,
                  (char*)Bs + (it * 512 + wid * 64) * 16);
    }
    float4 xa[2], xb[2];
#pragma unroll
    for (int it = 0; it < 2; ++it) {
      int L = it * 512 + tid;
      int r = L >> 3, s = L & 7;
      int c = s ^ (r & 7);
      const float* ga = A + (size_t)(m0 + r) * 512 + k0 + c * 8;
      xa[it] = *reinterpret_cast<const float4*>(ga);
      xb[it] = *reinterpret_cast<const float4*>(ga + 4);
    }
#pragma unroll
    for (int it = 0; it < 2; ++it) {
      int L = it * 512 + tid;
      u16x8 o;
      o[0] = f2b(xa[it].x); o[1] = f2b(xa[it].y);
      o[2] = f2b(xa[it].z); o[3] = f2b(xa[it].w);
      o[4] = f2b(xb[it].x); o[5] = f2b(xb[it].y);
      o[6] = f2b(xb[it].z); o[7] = f2b(xb[it].w);
      *(u16x8*)((char*)As + L * 16) = o;
    }
    __syncthreads();
#pragma unroll
    for (int kh = 0; kh < 2; ++kh) {
      bf16x8 af[4], bfr[8];
#pragma unroll
      for (int m = 0; m < 4; ++m)
        af[m] = *(const bf16x8*)((const char*)As + aoff[kh] + m * 2048);
#pragma unroll
      for (int n = 0; n < 8; ++n)
        bfr[n] = *(const bf16x8*)((const char*)Bs + boff[kh] + n * 2048);
#pragma unroll
      for (int m = 0; m < 4; ++m)
#pragma unroll
        for (int n = 0; n < 8; ++n)
          acc[m][n] = __builtin_amdgcn_mfma_f32_16x16x32_bf16(af[m], bfr[n], acc[m][n], 0, 0, 0);
    }
  }

  const int gn0 = wcn * 128 + l15;
  float bv[8];
#pragma unroll
  for (int n = 0; n < 8; ++n) bv[n] = bias[gn0 + n * 16];
#pragma unroll
  for (int m = 0; m < 4; ++m)
#pragma unroll
    for (int reg = 0; reg < 4; ++reg) {
      int gm = m0 + wr * 64 + m * 16 + lh * 4 + reg;
#pragma unroll
      for (int n = 0; n < 8; ++n)
        C[(size_t)gm * 512 + gn0 + n * 16] = f2b(acc[m][n][reg] + bv[n]);
    }
}

// ---------------------------------------------------------------------------
// Strip output GEMM, double-buffered: out_f32 = A_bf16 @ Bt^T + bias.
// ---------------------------------------------------------------------------
__global__ __launch_bounds__(512) void gemm_out(
    const u16* __restrict__ A, const u16* __restrict__ Bt,
    const float* __restrict__ bias, float* __restrict__ C)
{
  __shared__ u16 As[2][4096];
  __shared__ u16 Bs[2][16384];
  const int tid = threadIdx.x;
  const int lane = tid & 63, wid = tid >> 6;
  const int wr = wid >> 2, wcn = wid & 3;
  const int l15 = lane & 15, lh = lane >> 4;
  const int sx = (l15 >> 1) & 3;
  const int m0 = blockIdx.x * 128;
  const int rr = tid >> 2, sp = tid & 3;
  const int ssw = sp ^ ((rr >> 1) & 3);

  const f32x4 fz = {0.f, 0.f, 0.f, 0.f};
  f32x4 acc[4][8];
#pragma unroll
  for (int m = 0; m < 4; ++m)
#pragma unroll
    for (int n = 0; n < 8; ++n) acc[m][n] = fz;

  const int aoff0 = (wr * 64 + l15) * 64 + ((lh ^ sx) << 4);
  const int boff0 = (wcn * 128 + l15) * 64 + ((lh ^ sx) << 4);

  {
#pragma unroll
    for (int it = 0; it < 4; ++it)
      gload_lds16(Bt + (size_t)(it * 128 + rr) * 512 + ssw * 8,
                  (char*)Bs[0] + (it * 512 + wid * 64) * 16);
    gload_lds16(A + (size_t)(m0 + rr) * 512 + ssw * 8,
                (char*)As[0] + (wid * 64) * 16);
  }
  __syncthreads();

#pragma unroll 2
  for (int t = 0; t < 16; ++t) {
    const int cur = t & 1, nxt = cur ^ 1;
    if (t < 15) {
      const int k0 = (t + 1) * 32;
#pragma unroll
      for (int it = 0; it < 4; ++it)
        gload_lds16(Bt + (size_t)(it * 128 + rr) * 512 + k0 + ssw * 8,
                    (char*)Bs[nxt] + (it * 512 + wid * 64) * 16);
      gload_lds16(A + (size_t)(m0 + rr) * 512 + k0 + ssw * 8,
                  (char*)As[nxt] + (wid * 64) * 16);
    }
    bf16x8 af[4], bfr[8];
#pragma unroll
    for (int m = 0; m < 4; ++m)
      af[m] = *(const bf16x8*)((const char*)As[cur] + aoff0 + m * 1024);
#pragma unroll
    for (int n = 0; n < 8; ++n)
      bfr[n] = *(const bf16x8*)((const char*)Bs[cur] + boff0 + n * 1024);
#pragma unroll
    for (int m = 0; m < 4; ++m)
#pragma unroll
      for (int n = 0; n < 8; ++n)
        acc[m][n] = __builtin_amdgcn_mfma_f32_16x16x32_bf16(af[m], bfr[n], acc[m][n], 0, 0, 0);
    __syncthreads();
  }

  const int gn0 = wcn * 128 + l15;
  float bv[8];
#pragma unroll
  for (int n = 0; n < 8; ++n) bv[n] = bias[gn0 + n * 16];
#pragma unroll
  for (int m = 0; m < 4; ++m)
#pragma unroll
    for (int reg = 0; reg < 4; ++reg) {
      int gm = m0 + wr * 64 + m * 16 + lh * 4 + reg;
#pragma unroll
      for (int n = 0; n < 8; ++n)
        C[(size_t)gm * 512 + gn0 + n * 16] = acc[m][n][reg] + bv[n];
    }
}

// ---------------------------------------------------------------------------
// pq/pk GEMM (small): bf16 out. 128x128 tiles, z selects set. Bt is [n][k].
// ---------------------------------------------------------------------------
__global__ __launch_bounds__(256) void gemm_pp(
    const u16* __restrict__ A,
    const u16* __restrict__ Bt0, const float* __restrict__ bi0, u16* __restrict__ C0,
    const u16* __restrict__ Bt1, const float* __restrict__ bi1, u16* __restrict__ C1)
{
  const u16* Bt; const float* bias; u16* C;
  if (blockIdx.z == 0) { Bt = Bt0; bias = bi0; C = C0; }
  else                 { Bt = Bt1; bias = bi1; C = C1; }

  __shared__ u16 As[8192];   // 128 x 64
  __shared__ u16 Bs[8192];   // 128 x 64
  const int tid = threadIdx.x;
  const int lane = tid & 63, wid = tid >> 6;
  const int wr = wid >> 1, wc = wid & 1;
  const int l15 = lane & 15, lh = lane >> 4, l7 = lane & 7;
  const int m0 = blockIdx.x * 128, n0 = blockIdx.y * 128;

  const f32x4 fz = {0.f, 0.f, 0.f, 0.f};
  f32x4 acc[4][4];
#pragma unroll
  for (int m = 0; m < 4; ++m)
#pragma unroll
    for (int n = 0; n < 4; ++n) acc[m][n] = fz;

  int aoff[2], boff[2];
#pragma unroll
  for (int kh = 0; kh < 2; ++kh) {
    int slot = ((kh * 4 + lh) ^ l7) << 4;
    aoff[kh] = (wr * 64 + l15) * 128 + slot;
    boff[kh] = (wc * 64 + l15) * 128 + slot;
  }

  for (int k0 = 0; k0 < 512; k0 += 64) {
    __syncthreads();
#pragma unroll
    for (int it = 0; it < 4; ++it) {
      int L = it * 256 + tid;
      int r = L >> 3, s = L & 7;
      int c = s ^ (r & 7);
      gload_lds16(A  + (size_t)(m0 + r) * 512 + k0 + c * 8,
                  (char*)As + (it * 256 + wid * 64) * 16);
      gload_lds16(Bt + (size_t)(n0 + r) * 512 + k0 + c * 8,
                  (char*)Bs + (it * 256 + wid * 64) * 16);
    }
    __syncthreads();
#pragma unroll
    for (int kh = 0; kh < 2; ++kh) {
      bf16x8 af[4], bfr[4];
#pragma unroll
      for (int m = 0; m < 4; ++m)
        af[m] = *(const bf16x8*)((const char*)As + aoff[kh] + m * 2048);
#pragma unroll
      for (int n = 0; n < 4; ++n)
        bfr[n] = *(const bf16x8*)((const char*)Bs + boff[kh] + n * 2048);
#pragma unroll
      for (int m = 0; m < 4; ++m)
#pragma unroll
        for (int n = 0; n < 4; ++n)
          acc[m][n] = __builtin_amdgcn_mfma_f32_16x16x32_bf16(af[m], bfr[n], acc[m][n], 0, 0, 0);
    }
  }

  const int gn0 = n0 + wc * 64 + l15;
  float bv[4];
#pragma unroll
  for (int n = 0; n < 4; ++n) bv[n] = bias[gn0 + n * 16];
#pragma unroll
  for (int m = 0; m < 4; ++m)
#pragma unroll
    for (int reg = 0; reg < 4; ++reg) {
      int gm = m0 + wr * 64 + m * 16 + lh * 4 + reg;
#pragma unroll
      for (int n = 0; n < 4; ++n)
        C[(size_t)gm * 512 + gn0 + n * 16] = f2b(acc[m][n][reg] + bv[n]);
    }
}

// ---------------------------------------------------------------------------
// Fused pooled attention (flash-style): replaces qk_mfma + rs_inv + pv_mfma.
// One block per (bh, 128-wq tile): loop 8 wk-tiles of 64:
//   P = exp(SCALE * pq.pk) (f32, rowsum accumulated) -> bf16 LDS ->
//   out[128x448] += P @ pvT-slice.  Epilogue: *1/rowsum + residual -> X2.
// 512 thr = 8 waves. Out wave-tile 64x112 (acc 4x7). LDS ~96.5KB.
// bh = blockIdx.x & 63 co-schedules same-bh blocks on one XCD.
// ---------------------------------------------------------------------------
__global__ __launch_bounds__(512) void pattn(
    const u16* __restrict__ pq, const u16* __restrict__ pk,
    const u16* __restrict__ pvT, const u16* __restrict__ attn,
    u16* __restrict__ X2)
{
  __shared__ u16 Aq[8192];     // 128 x 64  pq tile (persistent)
  __shared__ u16 Bk[4096];     // 64 x 64   pk tile
  __shared__ u16 Pl[8192];     // 128 x 64  P (bf16)
  __shared__ u16 Vt[28672];    // 448 x 64  pvT tile
  __shared__ float rsl[128];   // row sums

  const int tid = threadIdx.x;
  const int lane = tid & 63, wid = tid >> 6;
  const int wr = wid >> 2, wcn = wid & 3;      // out wave grid 2 x 4
  const int l15 = lane & 15, lh = lane >> 4, l7 = lane & 7;
  const int bh = blockIdx.x & 63;
  const int wq0 = (blockIdx.x >> 6) * 128;
  const int b = bh >> 3, h = bh & 7;

  const f32x4 fz = {0.f, 0.f, 0.f, 0.f};
  f32x4 acc[4][7];
#pragma unroll
  for (int m = 0; m < 4; ++m)
#pragma unroll
    for (int n = 0; n < 7; ++n) acc[m][n] = fz;
  float rs4[4] = {0.f, 0.f, 0.f, 0.f};

  // stage pq once (128 x 64)
#pragma unroll
  for (int it = 0; it < 2; ++it) {
    int L = it * 512 + tid;
    int r = L >> 3, s = L & 7;
    int c = s ^ (r & 7);
    gload_lds16(pq + ((size_t)b * 512 + wq0 + r) * 512 + h * 64 + c * 8,
                (char*)Aq + L * 16);
  }

  int slotk[2];
#pragma unroll
  for (int kh = 0; kh < 2; ++kh) slotk[kh] = ((kh * 4 + lh) ^ l7) << 4;

  for (int wk0 = 0; wk0 < 512; wk0 += 64) {
    // stage pk (64x64) and pvT slice (448x64)
    {
      int L = tid;
      int r = L >> 3, s = L & 7;
      int c = s ^ (r & 7);
      gload_lds16(pk + ((size_t)b * 512 + wk0 + r) * 512 + h * 64 + c * 8,
                  (char*)Bk + L * 16);
    }
#pragma unroll
    for (int it = 0; it < 7; ++it) {
      int L = it * 512 + tid;
      int r = L >> 3, s = L & 7;
      int c = s ^ (r & 7);
      gload_lds16(pvT + ((size_t)bh * 448 + r) * 512 + wk0 + c * 8,
                  (char*)Vt + L * 16);
    }
    __syncthreads();

    // P-phase: wave wid computes P rows [wid*16, wid*16+16) x 64 cols
    f32x4 pacc[4];
#pragma unroll
    for (int n = 0; n < 4; ++n) pacc[n] = fz;
#pragma unroll
    for (int kh = 0; kh < 2; ++kh) {
      bf16x8 af = *(const bf16x8*)((const char*)Aq + (wid * 16 + l15) * 128 + slotk[kh]);
#pragma unroll
      for (int n = 0; n < 4; ++n) {
        bf16x8 bfr = *(const bf16x8*)((const char*)Bk + (n * 16 + l15) * 128 + slotk[kh]);
        pacc[n] = __builtin_amdgcn_mfma_f32_16x16x32_bf16(af, bfr, pacc[n], 0, 0, 0);
      }
    }
    // exp + rowsum + write P to LDS (swizzled, bf16)
#pragma unroll
    for (int n = 0; n < 4; ++n)
#pragma unroll
      for (int reg = 0; reg < 4; ++reg) {
        float e = expf(pacc[n][reg] * SCALE_);
        rs4[reg] += e;
        int prow = wid * 16 + lh * 4 + reg;
        int pcol = n * 16 + l15;
        int phys = (pcol >> 3) ^ (prow & 7);
        *(u16*)((char*)Pl + prow * 128 + phys * 16 + (pcol & 7) * 2) = f2b(e);
      }
    __syncthreads();

    // out-phase: acc[128x448] += P @ Vt^T
#pragma unroll
    for (int kh = 0; kh < 2; ++kh) {
      bf16x8 af[4], bfr[7];
#pragma unroll
      for (int m = 0; m < 4; ++m)
        af[m] = *(const bf16x8*)((const char*)Pl + (wr * 64 + m * 16 + l15) * 128 + slotk[kh]);
#pragma unroll
      for (int n = 0; n < 7; ++n)
        bfr[n] = *(const bf16x8*)((const char*)Vt + (wcn * 112 + n * 16 + l15) * 128 + slotk[kh]);
#pragma unroll
      for (int m = 0; m < 4; ++m)
#pragma unroll
        for (int n = 0; n < 7; ++n)
          acc[m][n] = __builtin_amdgcn_mfma_f32_16x16x32_bf16(af[m], bfr[n], acc[m][n], 0, 0, 0);
    }
    __syncthreads();
  }

  // rowsum reduce across the 16-lane group -> rsl
#pragma unroll
  for (int reg = 0; reg < 4; ++reg) {
    float v = rs4[reg];
    v += __shfl_xor(v, 1);
    v += __shfl_xor(v, 2);
    v += __shfl_xor(v, 4);
    v += __shfl_xor(v, 8);
    if (l15 == 0) rsl[wid * 16 + lh * 4 + reg] = v;
  }
  __syncthreads();

  // epilogue: scale + residual -> X2
#pragma unroll
  for (int m = 0; m < 4; ++m)
#pragma unroll
    for (int reg = 0; reg < 4; ++reg) {
      int lrow = wr * 64 + m * 16 + lh * 4 + reg;     // 0..127
      int gm = wq0 + lrow;                            // global wq
      float ri = 1.0f / rsl[lrow];
#pragma unroll
      for (int n = 0; n < 7; ++n) {
        int nd = wcn * 112 + n * 16 + l15;            // 0..447
        int nt = nd >> 6, d = nd & 63;
        float res = b2f(attn[((size_t)b * 4096 + gm * 8 + nt + 1) * 512 + h * 64 + d]);
        X2[((size_t)b * 3584 + gm * 7 + nt) * 512 + h * 64 + d] =
            f2b(acc[m][n][reg] * ri + res);
      }
    }
}

// ---------------------------------------------------------------------------
// Window attention (bf16 in/out), fused q 5-tap smoothing. fp32 math.
// One 64-thread block per (h, w, b).  [round-5 proven config]
// ---------------------------------------------------------------------------
__global__ __launch_bounds__(64) void attn_win(
    const u16* kp, const u16* vp, const u16* qp0, u16* attn)
{
  const int h = blockIdx.x, w = blockIdx.y, b = blockIdx.z;
  const int t = threadIdx.x;
  __shared__ float ks[8][68], vs[8][68], qr[12][68], qs[8][68], Ps[8][9];
  const size_t base = ((size_t)b * 4096 + (size_t)w * 8) * 512 + h * 64;

  {
    int i = t >> 3, dg = t & 7;
    u16x8 kv = *(const u16x8*)(kp + base + (size_t)i * 512 + dg * 8);
    u16x8 vv = *(const u16x8*)(vp + base + (size_t)i * 512 + dg * 8);
#pragma unroll
    for (int e = 0; e < 8; ++e) {
      ks[i][dg * 8 + e] = b2f(kv[e]);
      vs[i][dg * 8 + e] = b2f(vv[e]);
    }
  }
#pragma unroll
  for (int l = 0; l < 2; ++l) {
    int L = t + l * 64;
    if (L < 96) {
      int i = L >> 3, dg = L & 7;
      int m = w * 8 - 2 + i;
      if (m >= 0 && m < 4096) {
        u16x8 qv = *(const u16x8*)(qp0 + ((size_t)b * 4096 + m) * 512 + h * 64 + dg * 8);
#pragma unroll
        for (int e = 0; e < 8; ++e) qr[i][dg * 8 + e] = b2f(qv[e]);
      } else {
#pragma unroll
        for (int e = 0; e < 8; ++e) qr[i][dg * 8 + e] = 0.0f;
      }
    }
  }
  __syncthreads();
#pragma unroll
  for (int j = 0; j < 8; ++j)
    qs[j][t] = 0.2f * (qr[j][t] + qr[j + 1][t] + qr[j + 2][t] + qr[j + 3][t] + qr[j + 4][t]);
  __syncthreads();

  const int qi = t >> 3, kj = t & 7;
  float s = 0.0f;
#pragma unroll
  for (int d = 0; d < 64; ++d) s = fmaf(qs[qi][d], ks[kj][d], s);
  s *= SCALE_;
  float mx = s;
  mx = fmaxf(mx, __shfl_xor(mx, 1));
  mx = fmaxf(mx, __shfl_xor(mx, 2));
  mx = fmaxf(mx, __shfl_xor(mx, 4));
  float e = expf(s - mx);
  float sum = e;
  sum += __shfl_xor(sum, 1);
  sum += __shfl_xor(sum, 2);
  sum += __shfl_xor(sum, 4);
  Ps[qi][kj] = e / sum;
  __syncthreads();

  float o[8];
#pragma unroll
  for (int c = 0; c < 8; ++c) o[c] = 0.0f;
#pragma unroll
  for (int tt = 0; tt < 8; ++tt) {
    float pw = Ps[qi][tt];
#pragma unroll
    for (int c = 0; c < 8; ++c) o[c] = fmaf(pw, vs[tt][kj * 8 + c], o[c]);
  }
  u16x8 ov;
#pragma unroll
  for (int c = 0; c < 8; ++c) ov[c] = f2b(o[c]);
  *(u16x8*)(attn + base + (size_t)qi * 512 + kj * 8) = ov;
}

// ---------------------------------------------------------------------------
// Build pvT[bh][n=t*64+d][w2] = attn[b][8*w2+t+1][h*64+d]  (bf16)
// ---------------------------------------------------------------------------
__global__ __launch_bounds__(256) void pvt_build(const u16* attn, u16* pvT)
{
  const int bh = blockIdx.x;
  const int b = bh >> 3, h = bh & 7;
  const int w0 = blockIdx.y * 32;
  __shared__ u16 TL[448 * 40];
  const int tid = threadIdx.x;
#pragma unroll
  for (int it = 0; it < 8; ++it) {
    int L = it * 256 + tid;
    int dg = L & 7, r = L >> 3;
    int w2l = r >> 3, tt = r & 7;
    if (tt < 7) {
      int m = 8 * (w0 + w2l) + tt + 1;
      u16x8 v = *(const u16x8*)(attn + ((size_t)b * 4096 + m) * 512 + h * 64 + dg * 8);
#pragma unroll
      for (int e = 0; e < 8; ++e)
        TL[(tt * 64 + dg * 8 + e) * 40 + w2l] = v[e];
    }
  }
  __syncthreads();
#pragma unroll
  for (int it = 0; it < 7; ++it) {
    int L = it * 256 + tid;
    int n = L >> 2, seg = L & 3;
    u16x8 v = *(const u16x8*)(&TL[n * 40 + seg * 8]);
    *(u16x8*)(pvT + ((size_t)bh * 448 + n) * 512 + w0 + seg * 8) = v;
  }
}

// ---------------------------------------------------------------------------
// LayerNorm + exact GELU on window token 0 (bf16 in/out). One wave per row.
// ---------------------------------------------------------------------------
__global__ __launch_bounds__(64) void ln_gelu(
    const u16* attn, const float* g, const float* be, u16* wt)
{
  const int r = blockIdx.x;            // r = b*512 + w
  const int b = r >> 9, w = r & 511;
  const int t = threadIdx.x;
  const u16* x = attn + (((size_t)b * 4096) + (size_t)w * 8) * 512;

  u16x8 v = *(const u16x8*)(x + t * 8);
  float xv[8];
  float s1 = 0.f, s2 = 0.f;
#pragma unroll
  for (int e = 0; e < 8; ++e) {
    xv[e] = b2f(v[e]);
    s1 += xv[e]; s2 += xv[e] * xv[e];
  }
#pragma unroll
  for (int off = 1; off < 64; off <<= 1) {
    s1 += __shfl_xor(s1, off);
    s2 += __shfl_xor(s2, off);
  }
  const float mu  = s1 * (1.0f / 512.0f);
  const float var = s2 * (1.0f / 512.0f) - mu * mu;
  const float inv = 1.0f / sqrtf(var + EPS_);

  const int d0 = t * 8;
  float4 g0 = *reinterpret_cast<const float4*>(g + d0);
  float4 g1 = *reinterpret_cast<const float4*>(g + d0 + 4);
  float4 b0 = *reinterpret_cast<const float4*>(be + d0);
  float4 b1 = *reinterpret_cast<const float4*>(be + d0 + 4);
  float gv[8] = {g0.x, g0.y, g0.z, g0.w, g1.x, g1.y, g1.z, g1.w};
  float bvv[8] = {b0.x, b0.y, b0.z, b0.w, b1.x, b1.y, b1.z, b1.w};
  const float k2 = 0.70710678118654752f;
  u16x8 ov;
#pragma unroll
  for (int e = 0; e < 8; ++e) {
    float y = (xv[e] - mu) * inv * gv[e] + bvv[e];
    ov[e] = f2b(0.5f * y * (1.0f + erff(y * k2)));
  }
  *(u16x8*)(wt + (size_t)r * 512 + d0) = ov;
}

// ---------------------------------------------------------------------------
extern "C" void kernel_launch(void* const* d_in, const int* in_sizes, int n_in,
                              void* d_out, int out_size, void* d_ws, size_t ws_size,
                              hipStream_t stream)
{
  const float* k_in = (const float*)d_in[0];
  const float* v_in = (const float*)d_in[1];
  const float* q_in = (const float*)d_in[2];
  const float* Wk  = (const float*)d_in[4];
  const float* bk  = (const float*)d_in[5];
  const float* Wv  = (const float*)d_in[6];
  const float* bv  = (const float*)d_in[7];
  const float* Wq  = (const float*)d_in[8];
  const float* bq  = (const float*)d_in[9];
  const float* lng = (const float*)d_in[10];
  const float* lnb = (const float*)d_in[11];
  const float* Wpq = (const float*)d_in[12];
  const float* bpq = (const float*)d_in[13];
  const float* Wpk = (const float*)d_in[14];
  const float* bpk = (const float*)d_in[15];
  const float* Wo  = (const float*)d_in[16];
  const float* bo  = (const float*)d_in[17];
  float* out = (float*)d_out;

  char* ws = (char*)d_ws;
  const size_t MB = 1024 * 1024;
  u16* wtb  = (u16*)(ws);                 // 6 x 512KB transposed bf16 weights
  u16* kp   = (u16*)(ws + 16 * MB);
  u16* vp   = (u16*)(ws + 52 * MB);
  u16* qp0  = (u16*)(ws + 88 * MB);
  u16* attn = (u16*)(ws + 124 * MB);
  // phase 2 (kp/vp/qp0 regions reused after attn_win)
  u16*   wt    = (u16*)(ws + 16 * MB);
  u16*   pq    = (u16*)(ws + 20 * MB);
  u16*   pk    = (u16*)(ws + 28 * MB);
  u16*   pvT   = (u16*)(ws + 76 * MB);
  u16*   X2    = (u16*)(ws + 160 * MB);

  u16* Wkt  = wtb;
  u16* Wvt  = wtb + 1 * 262144;
  u16* Wqt  = wtb + 2 * 262144;
  u16* Wpqt = wtb + 3 * 262144;
  u16* Wpkt = wtb + 4 * 262144;
  u16* Wot  = wtb + 5 * 262144;

  wconv<<<dim3(8, 8, 6), 256, 0, stream>>>(Wk, Wv, Wq, Wpq, Wpk, Wo, wtb);

  gemm_proj<<<dim3(256, 1, 3), 512, 0, stream>>>(
      k_in, Wkt, bk, kp,
      v_in, Wvt, bv, vp,
      q_in, Wqt, bq, qp0);

  attn_win<<<dim3(8, 512, 8), 64, 0, stream>>>(kp, vp, qp0, attn);
  pvt_build<<<dim3(64, 16), 256, 0, stream>>>(attn, pvT);
  ln_gelu<<<4096, 64, 0, stream>>>(attn, lng, lnb, wt);

  gemm_pp<<<dim3(32, 4, 2), 256, 0, stream>>>(
      wt, Wpqt, bpq, pq, Wpkt, bpk, pk);

  // fused pooled attention: QK^T + softmax + PV + residual -> X2
  pattn<<<256, 512, 0, stream>>>(pq, pk, pvT, attn, X2);

  gemm_out<<<dim3(224, 1, 1), 512, 0, stream>>>(X2, Wot, bo, out);
}